// Round 1
// baseline (373.632 us; speedup 1.0000x reference)
//
#include <hip/hip_runtime.h>
#include <cmath>
#include <algorithm>

// FFA regressor for MI355X.
// Decomposition: per config (ds, bins):
//   pass A: blocks of G=2^S0 rows, init (downsample+fold-reshape) + stages 1..S0 in LDS,
//           write padded rows to scratch ordered [seq][block j][row p][c].
//   pass B: for each p, gather row p of all M=2^(K-S0) blocks, run stages S0+1..K
//           (local FFA of M rows with extra shift p*2^(t-1)), fuse max/median/SNR.
// LDS is column-major (stride G, multiple of 32) -> all stage accesses <=2-way bank aliasing.

constexpr int NSEQ    = 32;       // 8*4
constexpr int NLEN    = 262144;
constexpr int OUTROWS = 81920;

constexpr int cilog2(int v) { int r = 0; while (v > 1) { v >>= 1; ++r; } return r; }

__global__ __launch_bounds__(256)
void std_kernel(const float* __restrict__ x, float* __restrict__ rstd)
{
    const int seq = blockIdx.x;
    const float4* xp = reinterpret_cast<const float4*>(x + (size_t)seq * NLEN);
    float s = 0.f, s2 = 0.f;
    for (int i = threadIdx.x; i < NLEN / 4; i += 256) {
        float4 v = xp[i];
        s  += (v.x + v.y) + (v.z + v.w);
        s2 += (v.x * v.x + v.y * v.y) + (v.z * v.z + v.w * v.w);
    }
    __shared__ float ls[256], ls2[256];
    ls[threadIdx.x] = s; ls2[threadIdx.x] = s2;
    __syncthreads();
    for (int off = 128; off > 0; off >>= 1) {
        if (threadIdx.x < off) {
            ls[threadIdx.x]  += ls[threadIdx.x + off];
            ls2[threadIdx.x] += ls2[threadIdx.x + off];
        }
        __syncthreads();
    }
    if (threadIdx.x == 0) {
        const float n = (float)NLEN;
        float var = (ls2[0] - ls[0] * ls[0] / n) / (n - 1.f);
        rstd[seq] = rsqrtf(var);
    }
}

// ---------------- pass A ----------------
template<int DS, int BINS, int S0, int M, int CPADG>
__global__ __launch_bounds__(256)
void passA(const float* __restrict__ x, float* __restrict__ scr, int R, int seq0)
{
    constexpr int G = 1 << S0;
    __shared__ float buf[2][BINS * G];      // column-major: [c*G + row]
    const int t   = threadIdx.x;            // G/2 threads = pair index
    const int blk = blockIdx.x;             // [0, M)
    const int sl  = blockIdx.y;             // local seq
    const int seq = seq0 + sl;
    const float* xs = x + (size_t)seq * NLEN;

    // init: rows of the folded matrix straight from x (downsample is exact w=0.5)
    #pragma unroll
    for (int it = 0; it < 2; ++it) {
        const int lr = t + it * (G / 2);
        const int gr = blk * G + lr;
        if (gr < R) {
            #pragma unroll
            for (int c = 0; c < BINS; ++c) {
                const int j = gr * BINS + c;
                float v;
                if (DS == 2) {
                    float2 p2 = *reinterpret_cast<const float2*>(xs + 2 * j);
                    v = 0.5f * (p2.x + p2.y);
                } else {
                    v = 0.5f * (xs[4 * j + 1] + xs[4 * j + 2]);
                }
                buf[0][c * G + lr] = v;
            }
        } else {
            #pragma unroll
            for (int c = 0; c < BINS; ++c) buf[0][c * G + lr] = 0.f;
        }
    }
    __syncthreads();

    // stages 1..S0; thread = output pair-row (2 outputs share both source rows)
    for (int s = 1; s <= S0; ++s) {
        const float* src = buf[(s - 1) & 1];
        float*       dst = buf[s & 1];
        const int half    = 1 << (s - 1);
        const int qp      = t & (half - 1);
        const int grpbase = (t >> (s - 1)) << s;
        const int rA = grpbase + qp;
        const int rB = rA + half;
        const int ro = grpbase + 2 * qp;
        const int shift = qp % BINS;
        int sc = (shift == 0) ? 0 : BINS - shift;          // (0 - shift) mod BINS
        const int scm1 = (sc == 0) ? BINS - 1 : sc - 1;
        float bprev = src[scm1 * G + rB];
        #pragma unroll
        for (int c = 0; c < BINS; ++c) {
            float a  = src[c * G + rA];
            float bc = src[sc * G + rB];
            float2 o; o.x = a + bc; o.y = a + bprev;       // rows ro, ro+1
            *reinterpret_cast<float2*>(&dst[c * G + ro]) = o;
            bprev = bc;
            ++sc; if (sc == BINS) sc = 0;
        }
        __syncthreads();
    }

    // writeout: scratch[((sl*M + blk)*G + lr)*CPADG + c], vectorized
    const float* fin = buf[S0 & 1];
    #pragma unroll
    for (int it = 0; it < 2; ++it) {
        const int lr = t + it * (G / 2);
        float vals[CPADG];
        #pragma unroll
        for (int c = 0; c < CPADG; ++c) vals[c] = (c < BINS) ? fin[c * G + lr] : 0.f;
        float4* dst4 = reinterpret_cast<float4*>(scr + ((size_t)(sl * M + blk) * G + lr) * CPADG);
        #pragma unroll
        for (int c4 = 0; c4 < CPADG / 4; ++c4)
            dst4[c4] = make_float4(vals[4 * c4], vals[4 * c4 + 1], vals[4 * c4 + 2], vals[4 * c4 + 3]);
    }
}

// ---------------- pass B ----------------
template<int BINS, int S0, int K, int CPADG, int OUTOFF>
__global__ __launch_bounds__(256)
void passB(const float* __restrict__ scr, const float* __restrict__ rstd,
           float* __restrict__ out, float rsqrtR, int seq0)
{
    constexpr int G   = 1 << S0;
    constexpr int M   = 1 << (K - S0);   // rows per final block (= #passA blocks)
    constexpr int TS  = K - S0;          // tail stages
    constexpr int CST = M + 8;           // column stride (stagger p-groups across banks)
    constexpr int NCH = 128 / M;         // column chunks (pairs = M/2 lanes)
    constexpr int LCH = cilog2(NCH);
    constexpr int VCH = 64 / M;          // column chunks for load
    constexpr int LM  = cilog2(M);

    __shared__ float zb[4][2][BINS * CST];
    const int t   = threadIdx.x;
    const int w   = t >> 6;              // wave -> one p each
    const int l   = t & 63;
    const int p   = blockIdx.x * 4 + w;
    const int sl  = blockIdx.y;
    const int seq = seq0 + sl;

    // gather: z0[v] = scratch row (block j=v, row p)
    {
        const int v  = l & (M - 1);
        const int cc = l >> LM;
        const float* srow = scr + ((size_t)(sl * M + v) * G + p) * CPADG;
        for (int c = cc; c < BINS; c += VCH)
            zb[w][0][c * CST + v] = srow[c];
    }
    __syncthreads();

    // tail stages: size-M FFA with extra shift p*2^(s-1)
    for (int s = 1; s <= TS; ++s) {
        const float* src = zb[w][(s - 1) & 1];
        float*       dst = zb[w][s & 1];
        const int q  = l >> LCH;         // pair index [0, M/2)
        const int ch = l & (NCH - 1);    // column chunk
        const int half    = 1 << (s - 1);
        const int qp      = q & (half - 1);
        const int grpbase = (q >> (s - 1)) << s;
        const int vA = grpbase + qp;
        const int vB = vA + half;
        const int vo = grpbase + 2 * qp;
        const int shift = (qp + (p << (s - 1))) % BINS;
        for (int c = ch; c < BINS; c += NCH) {
            int sc0 = c - shift; if (sc0 < 0) sc0 += BINS;
            int sc1 = sc0 - 1;   if (sc1 < 0) sc1 += BINS;
            float a  = src[c * CST + vA];
            float b0 = src[sc0 * CST + vB];
            float b1 = src[sc1 * CST + vB];
            float2 o; o.x = a + b0; o.y = a + b1;
            *reinterpret_cast<float2*>(&dst[c * CST + vo]) = o;
        }
        __syncthreads();
    }

    // fused stats: max, lower median (partial selection sort, static indices), SNR
    if (l < M) {
        const float* z = zb[w][TS & 1];
        const int v = l;
        float a[BINS];
        #pragma unroll
        for (int c = 0; c < BINS; ++c) a[c] = z[c * CST + v];
        float mx = a[0];
        #pragma unroll
        for (int c = 1; c < BINS; ++c) mx = fmaxf(mx, a[c]);
        constexpr int MIDX = (BINS - 1) / 2;
        #pragma unroll
        for (int i = 0; i <= MIDX; ++i) {
            #pragma unroll
            for (int j = i + 1; j < BINS; ++j) {
                float lo = fminf(a[i], a[j]);
                float hi = fmaxf(a[i], a[j]);
                a[i] = lo; a[j] = hi;
            }
        }
        const float snr = (mx - a[MIDX]) * rstd[seq] * rsqrtR;
        out[(size_t)seq * OUTROWS + OUTOFF + p * M + v] = snr;
    }
}

// ---------------- host ----------------
template<int DS, int BINS, int K, int S0, int OUTOFF>
static void run_cfg(const float* x, const float* rstd, float* out, float* scr,
                    size_t avail, int R, hipStream_t stream)
{
    constexpr int G     = 1 << S0;
    constexpr int M     = 1 << (K - S0);
    constexpr int CPADG = (BINS + 3) & ~3;
    const float rsqrtR  = (float)(1.0 / std::sqrt((double)R));
    const size_t perSeq = (size_t)(1 << K) * CPADG * sizeof(float);
    int chunk = (int)std::min<size_t>(NSEQ, perSeq ? (avail / perSeq) : NSEQ);
    if (chunk < 1) chunk = 1;
    for (int s0 = 0; s0 < NSEQ; s0 += chunk) {
        const int ns = std::min(chunk, NSEQ - s0);
        hipLaunchKernelGGL((passA<DS, BINS, S0, M, CPADG>),
                           dim3(M, ns), dim3(G / 2), 0, stream, x, scr, R, s0);
        hipLaunchKernelGGL((passB<BINS, S0, K, CPADG, OUTOFF>),
                           dim3(G / 4, ns), dim3(256), 0, stream, scr, rstd, out, rsqrtR, s0);
    }
}

extern "C" void kernel_launch(void* const* d_in, const int* in_sizes, int n_in,
                              void* d_out, int out_size, void* d_ws, size_t ws_size,
                              hipStream_t stream)
{
    (void)in_sizes; (void)n_in; (void)out_size;
    const float* x = (const float*)d_in[0];
    float* out  = (float*)d_out;
    float* wsf  = (float*)d_ws;
    float* rstd = wsf;          // 32 floats
    float* scr  = wsf + 64;     // 256B-aligned scratch
    const size_t avail = (ws_size > 256) ? ws_size - 256 : 0;

    hipLaunchKernelGGL(std_kernel, dim3(NSEQ), dim3(256), 0, stream, x, rstd);

    // ds=2: L=131072, k=14, S0=9 ; ds=4: L=65536, k=12, S0=8
    run_cfg<2, 10, 14, 9, 0>     (x, rstd, out, scr, avail, 13107, stream);
    run_cfg<2, 11, 14, 9, 16384> (x, rstd, out, scr, avail, 11915, stream);
    run_cfg<2, 12, 14, 9, 32768> (x, rstd, out, scr, avail, 10922, stream);
    run_cfg<2, 13, 14, 9, 49152> (x, rstd, out, scr, avail, 10082, stream);
    run_cfg<4, 16, 12, 8, 65536> (x, rstd, out, scr, avail, 4096,  stream);
    run_cfg<4, 17, 12, 8, 69632> (x, rstd, out, scr, avail, 3855,  stream);
    run_cfg<4, 18, 12, 8, 73728> (x, rstd, out, scr, avail, 3640,  stream);
    run_cfg<4, 19, 12, 8, 77824> (x, rstd, out, scr, avail, 3449,  stream);
}

// Round 2
// 290.123 us; speedup vs baseline: 1.2878x; 1.2878x over previous
//
#include <hip/hip_runtime.h>
#include <cmath>
#include <algorithm>

// FFA regressor for MI355X.
// Decomposition per config (ds, bins):
//   pass A: blocks of G=2^S0 rows, init (downsample+fold-reshape) + stages 1..S0 in LDS,
//           write rows to scratch ordered [seq][row p][block j][c]  (coalesced passB reads).
//   pass B: for each p, gather row p of all M=2^(K-S0) blocks (contiguous!), run stages
//           S0+1..K (local FFA of M rows with extra shift p*2^(t-1)), fuse max/median/SNR.
// std(ddof=1) via two-phase deterministic reduction (1024 partial blocks + finalize).

constexpr int NSEQ    = 32;       // 8*4
constexpr int NLEN    = 262144;
constexpr int OUTROWS = 81920;
constexpr int STDCH   = 32;       // partial chunks per seq

constexpr int cilog2(int v) { int r = 0; while (v > 1) { v >>= 1; ++r; } return r; }

// ---------------- std: partial sums ----------------
__global__ __launch_bounds__(256)
void std_partial(const float* __restrict__ x, float2* __restrict__ part)
{
    const int seq = blockIdx.x, ch = blockIdx.y;
    constexpr int N4 = NLEN / 4 / STDCH;      // float4s per chunk = 2048
    const float4* xp = reinterpret_cast<const float4*>(x + (size_t)seq * NLEN) + (size_t)ch * N4;
    float s = 0.f, s2 = 0.f;
    for (int i = threadIdx.x; i < N4; i += 256) {
        float4 v = xp[i];
        s  += (v.x + v.y) + (v.z + v.w);
        s2 += (v.x * v.x + v.y * v.y) + (v.z * v.z + v.w * v.w);
    }
    // wave reduce (64 lanes)
    #pragma unroll
    for (int off = 32; off > 0; off >>= 1) {
        s  += __shfl_down(s, off, 64);
        s2 += __shfl_down(s2, off, 64);
    }
    __shared__ float2 ws[4];
    const int w = threadIdx.x >> 6, l = threadIdx.x & 63;
    if (l == 0) ws[w] = make_float2(s, s2);
    __syncthreads();
    if (threadIdx.x == 0) {
        float a = ws[0].x + ws[1].x + ws[2].x + ws[3].x;
        float b = ws[0].y + ws[1].y + ws[2].y + ws[3].y;
        part[seq * STDCH + ch] = make_float2(a, b);
    }
}

__global__ __launch_bounds__(64)
void std_final(const float2* __restrict__ part, float* __restrict__ rstd)
{
    const int seq = threadIdx.x;
    if (seq < NSEQ) {
        float s = 0.f, s2 = 0.f;
        for (int i = 0; i < STDCH; ++i) {
            float2 p = part[seq * STDCH + i];
            s += p.x; s2 += p.y;
        }
        const float n = (float)NLEN;
        rstd[seq] = rsqrtf((s2 - s * s / n) / (n - 1.f));
    }
}

// ---------------- pass A ----------------
template<int DS, int BINS, int S0, int M, int CPADG>
__global__ __launch_bounds__(256)
void passA(const float* __restrict__ x, float* __restrict__ scr, int R, int seq0)
{
    constexpr int G = 1 << S0;
    __shared__ float buf[2][BINS * G];      // column-major: [c*G + row]
    const int t   = threadIdx.x;            // G/2 threads = pair index
    const int blk = blockIdx.x;             // [0, M)
    const int sl  = blockIdx.y;             // local seq
    const int seq = seq0 + sl;
    const float* xs = x + (size_t)seq * NLEN;

    // init: rows of the folded matrix straight from x (downsample is exact w=0.5)
    #pragma unroll
    for (int it = 0; it < 2; ++it) {
        const int lr = t + it * (G / 2);
        const int gr = blk * G + lr;
        if (gr < R) {
            #pragma unroll
            for (int c = 0; c < BINS; ++c) {
                const int j = gr * BINS + c;
                float v;
                if (DS == 2) {
                    float2 p2 = *reinterpret_cast<const float2*>(xs + 2 * j);
                    v = 0.5f * (p2.x + p2.y);
                } else {
                    float4 p4 = *reinterpret_cast<const float4*>(xs + 4 * j);
                    v = 0.5f * (p4.y + p4.z);
                }
                buf[0][c * G + lr] = v;
            }
        } else {
            #pragma unroll
            for (int c = 0; c < BINS; ++c) buf[0][c * G + lr] = 0.f;
        }
    }
    __syncthreads();

    // stages 1..S0; thread = output pair-row (2 outputs share both source rows)
    for (int s = 1; s <= S0; ++s) {
        const float* src = buf[(s - 1) & 1];
        float*       dst = buf[s & 1];
        const int half    = 1 << (s - 1);
        const int qp      = t & (half - 1);
        const int grpbase = (t >> (s - 1)) << s;
        const int rA = grpbase + qp;
        const int rB = rA + half;
        const int ro = grpbase + 2 * qp;
        const int shift = qp % BINS;
        int sc = (shift == 0) ? 0 : BINS - shift;          // (0 - shift) mod BINS
        const int scm1 = (sc == 0) ? BINS - 1 : sc - 1;
        float bprev = src[scm1 * G + rB];
        #pragma unroll
        for (int c = 0; c < BINS; ++c) {
            float a  = src[c * G + rA];
            float bc = src[sc * G + rB];
            float2 o; o.x = a + bc; o.y = a + bprev;       // rows ro, ro+1
            *reinterpret_cast<float2*>(&dst[c * G + ro]) = o;
            bprev = bc;
            ++sc; if (sc == BINS) sc = 0;
        }
        __syncthreads();
    }

    // writeout: scratch[((sl*G + lr)*M + blk)*CPADG + c]  (per-lane 16B chunks)
    const float* fin = buf[S0 & 1];
    #pragma unroll
    for (int it = 0; it < 2; ++it) {
        const int lr = t + it * (G / 2);
        float vals[CPADG];
        #pragma unroll
        for (int c = 0; c < CPADG; ++c) vals[c] = (c < BINS) ? fin[c * G + lr] : 0.f;
        float4* dst4 = reinterpret_cast<float4*>(scr + ((size_t)(sl * G + lr) * M + blk) * CPADG);
        #pragma unroll
        for (int c4 = 0; c4 < CPADG / 4; ++c4)
            dst4[c4] = make_float4(vals[4 * c4], vals[4 * c4 + 1], vals[4 * c4 + 2], vals[4 * c4 + 3]);
    }
}

// ---------------- pass B ----------------
template<int BINS, int S0, int K, int CPADG, int OUTOFF>
__global__ __launch_bounds__(256)
void passB(const float* __restrict__ scr, const float* __restrict__ rstd,
           float* __restrict__ out, float rsqrtR, int seq0)
{
    constexpr int G   = 1 << S0;
    constexpr int M   = 1 << (K - S0);   // rows per final block (= #passA blocks)
    constexpr int TS  = K - S0;          // tail stages
    constexpr int CST = M + 8;           // column stride (stagger across banks)
    constexpr int NCH = 128 / M;         // column chunks (pairs = M/2 lanes)
    constexpr int LCH = cilog2(NCH);

    __shared__ float zb[4][2][BINS * CST];
    const int t   = threadIdx.x;
    const int w   = t >> 6;              // wave -> one p each
    const int l   = t & 63;
    const int p   = blockIdx.x * 4 + w;
    const int sl  = blockIdx.y;
    const int seq = seq0 + sl;

    // gather: contiguous M*CPADG floats per (sl,p), fully coalesced
    {
        const float* base = scr + (size_t)(sl * G + p) * M * CPADG;
        constexpr int TOT = M * CPADG;
        for (int idx = l; idx < TOT; idx += 64) {
            const int v = idx / CPADG;
            const int c = idx - v * CPADG;
            if (c < BINS) zb[w][0][c * CST + v] = base[idx];
        }
    }
    __syncthreads();

    // tail stages: size-M FFA with extra shift p*2^(s-1)
    for (int s = 1; s <= TS; ++s) {
        const float* src = zb[w][(s - 1) & 1];
        float*       dst = zb[w][s & 1];
        const int q  = l >> LCH;         // pair index [0, M/2)
        const int ch = l & (NCH - 1);    // column chunk
        const int half    = 1 << (s - 1);
        const int qp      = q & (half - 1);
        const int grpbase = (q >> (s - 1)) << s;
        const int vA = grpbase + qp;
        const int vB = vA + half;
        const int vo = grpbase + 2 * qp;
        const int shift = (qp + (p << (s - 1))) % BINS;
        for (int c = ch; c < BINS; c += NCH) {
            int sc0 = c - shift; if (sc0 < 0) sc0 += BINS;
            int sc1 = sc0 - 1;   if (sc1 < 0) sc1 += BINS;
            float a  = src[c * CST + vA];
            float b0 = src[sc0 * CST + vB];
            float b1 = src[sc1 * CST + vB];
            float2 o; o.x = a + b0; o.y = a + b1;
            *reinterpret_cast<float2*>(&dst[c * CST + vo]) = o;
        }
        __syncthreads();
    }

    // fused stats: max, lower median (partial selection sort, static indices), SNR
    if (l < M) {
        const float* z = zb[w][TS & 1];
        const int v = l;
        float a[BINS];
        #pragma unroll
        for (int c = 0; c < BINS; ++c) a[c] = z[c * CST + v];
        float mx = a[0];
        #pragma unroll
        for (int c = 1; c < BINS; ++c) mx = fmaxf(mx, a[c]);
        constexpr int MIDX = (BINS - 1) / 2;
        #pragma unroll
        for (int i = 0; i <= MIDX; ++i) {
            #pragma unroll
            for (int j = i + 1; j < BINS; ++j) {
                float lo = fminf(a[i], a[j]);
                float hi = fmaxf(a[i], a[j]);
                a[i] = lo; a[j] = hi;
            }
        }
        const float snr = (mx - a[MIDX]) * rstd[seq] * rsqrtR;
        out[(size_t)seq * OUTROWS + OUTOFF + p * M + v] = snr;
    }
}

// ---------------- host ----------------
template<int DS, int BINS, int K, int S0, int OUTOFF>
static void run_cfg(const float* x, const float* rstd, float* out, float* scr,
                    size_t avail, int R, hipStream_t stream)
{
    constexpr int G     = 1 << S0;
    constexpr int M     = 1 << (K - S0);
    constexpr int CPADG = (BINS + 3) & ~3;
    const float rsqrtR  = (float)(1.0 / std::sqrt((double)R));
    const size_t perSeq = (size_t)(1 << K) * CPADG * sizeof(float);
    int chunk = (int)std::min<size_t>(NSEQ, perSeq ? (avail / perSeq) : NSEQ);
    if (chunk < 1) chunk = 1;
    for (int s0 = 0; s0 < NSEQ; s0 += chunk) {
        const int ns = std::min(chunk, NSEQ - s0);
        hipLaunchKernelGGL((passA<DS, BINS, S0, M, CPADG>),
                           dim3(M, ns), dim3(G / 2), 0, stream, x, scr, R, s0);
        hipLaunchKernelGGL((passB<BINS, S0, K, CPADG, OUTOFF>),
                           dim3(G / 4, ns), dim3(256), 0, stream, scr, rstd, out, rsqrtR, s0);
    }
}

extern "C" void kernel_launch(void* const* d_in, const int* in_sizes, int n_in,
                              void* d_out, int out_size, void* d_ws, size_t ws_size,
                              hipStream_t stream)
{
    (void)in_sizes; (void)n_in; (void)out_size;
    const float* x = (const float*)d_in[0];
    float* out  = (float*)d_out;
    float* wsf  = (float*)d_ws;
    float*  rstd = wsf;                                  // 32 floats
    float2* part = reinterpret_cast<float2*>(wsf + 64);  // 32*32 float2 = 2048 floats
    float*  scr  = wsf + 64 + 2 * NSEQ * STDCH + 64;     // 256B-aligned scratch
    const size_t used  = ((size_t)(64 + 2 * NSEQ * STDCH + 64)) * sizeof(float);
    const size_t avail = (ws_size > used) ? ws_size - used : 0;

    hipLaunchKernelGGL(std_partial, dim3(NSEQ, STDCH), dim3(256), 0, stream, x, part);
    hipLaunchKernelGGL(std_final, dim3(1), dim3(64), 0, stream, part, rstd);

    // ds=2: L=131072, k=14, S0=9 ; ds=4: L=65536, k=12, S0=8
    run_cfg<2, 10, 14, 9, 0>     (x, rstd, out, scr, avail, 13107, stream);
    run_cfg<2, 11, 14, 9, 16384> (x, rstd, out, scr, avail, 11915, stream);
    run_cfg<2, 12, 14, 9, 32768> (x, rstd, out, scr, avail, 10922, stream);
    run_cfg<2, 13, 14, 9, 49152> (x, rstd, out, scr, avail, 10082, stream);
    run_cfg<4, 16, 12, 8, 65536> (x, rstd, out, scr, avail, 4096,  stream);
    run_cfg<4, 17, 12, 8, 69632> (x, rstd, out, scr, avail, 3855,  stream);
    run_cfg<4, 18, 12, 8, 73728> (x, rstd, out, scr, avail, 3640,  stream);
    run_cfg<4, 19, 12, 8, 77824> (x, rstd, out, scr, avail, 3449,  stream);
}

// Round 3
// 216.623 us; speedup vs baseline: 1.7248x; 1.3393x over previous
//
#include <hip/hip_runtime.h>
#include <cmath>

// FFA regressor for MI355X — fused: 4 dispatches total.
//   std_partial/std_final: two-phase ddof=1 std reduction.
//   passA_all: all 8 configs; blocks of G=2^S0 rows, init (exact w=0.5 downsample)
//              + stages 1..S0 in LDS (column-major, stride G), write scratch [p][v][c].
//   passB_all: all 8 configs; P=256/M p-values per block, gather (coalesced float4),
//              tail stages S0+1..K (extra shift p*2^(s-1)), full-lane max/median/SNR,
//              contiguous 256-float output store per block.

constexpr int NSEQ    = 32;
constexpr int NLEN    = 262144;
constexpr int OUTROWS = 81920;
constexpr int STDCH   = 32;

constexpr int cilog2(int v) { int r = 0; while (v > 1) { v >>= 1; ++r; } return r; }

// scratch float offsets per config (sizes: 32*2^K*CPADG)
constexpr size_t SCROFF[8] = {0, 6291456, 12582912, 18874368,
                              27262976, 29360128, 31981568, 34603008};

// ---------------- std ----------------
__global__ __launch_bounds__(256)
void std_partial(const float* __restrict__ x, float2* __restrict__ part)
{
    const int seq = blockIdx.x, ch = blockIdx.y;
    constexpr int N4 = NLEN / 4 / STDCH;
    const float4* xp = reinterpret_cast<const float4*>(x + (size_t)seq * NLEN) + (size_t)ch * N4;
    float s = 0.f, s2 = 0.f;
    for (int i = threadIdx.x; i < N4; i += 256) {
        float4 v = xp[i];
        s  += (v.x + v.y) + (v.z + v.w);
        s2 += (v.x * v.x + v.y * v.y) + (v.z * v.z + v.w * v.w);
    }
    #pragma unroll
    for (int off = 32; off > 0; off >>= 1) {
        s  += __shfl_down(s, off, 64);
        s2 += __shfl_down(s2, off, 64);
    }
    __shared__ float2 ws[4];
    const int w = threadIdx.x >> 6, l = threadIdx.x & 63;
    if (l == 0) ws[w] = make_float2(s, s2);
    __syncthreads();
    if (threadIdx.x == 0) {
        float a = ws[0].x + ws[1].x + ws[2].x + ws[3].x;
        float b = ws[0].y + ws[1].y + ws[2].y + ws[3].y;
        part[seq * STDCH + ch] = make_float2(a, b);
    }
}

__global__ __launch_bounds__(64)
void std_final(const float2* __restrict__ part, float* __restrict__ rstd)
{
    const int seq = threadIdx.x;
    if (seq < NSEQ) {
        float s = 0.f, s2 = 0.f;
        for (int i = 0; i < STDCH; ++i) {
            float2 p = part[seq * STDCH + i];
            s += p.x; s2 += p.y;
        }
        const float n = (float)NLEN;
        rstd[seq] = rsqrtf((s2 - s * s / n) / (n - 1.f));
    }
}

// ---------------- pass A body ----------------
template<int DS, int BINS, int K, int S0, int CPADG>
__device__ __forceinline__
void passA_body(float* __restrict__ buf, const float* __restrict__ xs,
                float* __restrict__ scrC, int R, int blk, int sl)
{
    constexpr int G      = 1 << S0;
    constexpr int M      = 1 << (K - S0);
    constexpr int CSPLIT = 512 / G;              // 1 (G=512) or 2 (G=256)
    constexpr int PAIRS  = G / 2;
    constexpr int H      = (BINS + CSPLIT - 1) / CSPLIT;
    const int t = threadIdx.x;
    float* b0 = buf;
    float* b1 = buf + BINS * G;

    // init
    for (int lr = t; lr < G; lr += 256) {
        const int gr = blk * G + lr;
        if (gr < R) {
            #pragma unroll
            for (int c = 0; c < BINS; ++c) {
                const int j = gr * BINS + c;
                float v;
                if constexpr (DS == 2) {
                    float2 p2 = *reinterpret_cast<const float2*>(xs + 2 * j);
                    v = 0.5f * (p2.x + p2.y);
                } else {
                    float4 p4 = *reinterpret_cast<const float4*>(xs + 4 * j);
                    v = 0.5f * (p4.y + p4.z);
                }
                b0[c * G + lr] = v;
            }
        } else {
            #pragma unroll
            for (int c = 0; c < BINS; ++c) b0[c * G + lr] = 0.f;
        }
    }
    __syncthreads();

    const int pr  = t & (PAIRS - 1);
    const int chi = (CSPLIT > 1) ? (t >> (S0 - 1)) : 0;
    const int c0  = chi * H;

    for (int s = 1; s <= S0; ++s) {
        float* src = (s & 1) ? b0 : b1;
        float* dst = (s & 1) ? b1 : b0;
        const int half    = 1 << (s - 1);
        const int qp      = pr & (half - 1);
        const int grpbase = (pr >> (s - 1)) << s;
        const int rA = grpbase + qp;
        const int rB = rA + half;
        const int ro = grpbase + 2 * qp;
        const int shift = qp % BINS;
        int sc = c0 - shift; if (sc < 0) sc += BINS;
        int scm1 = sc - 1;   if (scm1 < 0) scm1 += BINS;
        float bprev = src[scm1 * G + rB];
        #pragma unroll
        for (int i = 0; i < H; ++i) {
            const int c = c0 + i;
            if (c < BINS) {
                float a  = src[c * G + rA];
                float bc = src[sc * G + rB];
                float2 o; o.x = a + bc; o.y = a + bprev;
                *reinterpret_cast<float2*>(&dst[c * G + ro]) = o;
                bprev = bc;
                ++sc; if (sc == BINS) sc = 0;
            }
        }
        __syncthreads();
    }

    const float* fin = (S0 & 1) ? b1 : b0;
    for (int lr = t; lr < G; lr += 256) {
        float vals[CPADG];
        #pragma unroll
        for (int c = 0; c < CPADG; ++c) vals[c] = (c < BINS) ? fin[c * G + lr] : 0.f;
        float4* dst4 = reinterpret_cast<float4*>(scrC + ((size_t)(sl * G + lr) * M + blk) * CPADG);
        #pragma unroll
        for (int c4 = 0; c4 < CPADG / 4; ++c4)
            dst4[c4] = make_float4(vals[4 * c4], vals[4 * c4 + 1], vals[4 * c4 + 2], vals[4 * c4 + 3]);
    }
}

__global__ __launch_bounds__(256)
void passA_all(const float* __restrict__ x, float* __restrict__ scr)
{
    __shared__ float buf[2 * 13 * 512];
    const int b = blockIdx.x;
    if (b < 4096) {
        const int cfg = b >> 10, r = b & 1023, blk = r & 31, sl = r >> 5;
        const float* xs = x + (size_t)sl * NLEN;
        switch (cfg) {
            case 0: passA_body<2, 10, 14, 9, 12>(buf, xs, scr + SCROFF[0], 13107, blk, sl); break;
            case 1: passA_body<2, 11, 14, 9, 12>(buf, xs, scr + SCROFF[1], 11915, blk, sl); break;
            case 2: passA_body<2, 12, 14, 9, 12>(buf, xs, scr + SCROFF[2], 10922, blk, sl); break;
            default: passA_body<2, 13, 14, 9, 16>(buf, xs, scr + SCROFF[3], 10082, blk, sl); break;
        }
    } else {
        const int b2 = b - 4096;
        const int cfg = b2 >> 9, r = b2 & 511, blk = r & 15, sl = r >> 4;
        const float* xs = x + (size_t)sl * NLEN;
        switch (cfg) {
            case 0: passA_body<4, 16, 12, 8, 16>(buf, xs, scr + SCROFF[4], 4096, blk, sl); break;
            case 1: passA_body<4, 17, 12, 8, 20>(buf, xs, scr + SCROFF[5], 3855, blk, sl); break;
            case 2: passA_body<4, 18, 12, 8, 20>(buf, xs, scr + SCROFF[6], 3640, blk, sl); break;
            default: passA_body<4, 19, 12, 8, 20>(buf, xs, scr + SCROFF[7], 3449, blk, sl); break;
        }
    }
}

// ---------------- pass B body ----------------
template<int BINS, int K, int S0, int CPADG, int OUTOFF>
__device__ __forceinline__
void passB_body(float* __restrict__ zb, const float* __restrict__ scrC,
                const float* __restrict__ rstd, float* __restrict__ out,
                int R, int p_base, int sl)
{
    constexpr int G    = 1 << S0;
    constexpr int M    = 1 << (K - S0);
    constexpr int TS   = K - S0;          // note: M == 1<<TS
    constexpr int P    = 256 / M;         // p per block
    constexpr int P4   = P / 4;           // p per wave
    constexpr int CST  = M + 4;
    constexpr int BCST = BINS * CST;
    constexpr int NCH  = 128 / M;         // lanes per pair
    constexpr int LCH  = cilog2(NCH);

    const int t = threadIdx.x, w = t >> 6, l = t & 63;

    // gather: contiguous P*M*CPADG floats, float4 loads, scatter into zb
    {
        const float4* base4 = reinterpret_cast<const float4*>(
            scrC + ((size_t)sl * G + p_base) * M * CPADG);
        constexpr int TOT4 = P * M * CPADG / 4;
        for (int i = t; i < TOT4; i += 256) {
            float4 d = base4[i];
            const int fidx = i * 4;
            const int pg  = fidx / (M * CPADG);
            const int rem = fidx - pg * (M * CPADG);
            const int v   = rem / CPADG;
            const int cb  = rem - v * CPADG;
            float* zp = zb + pg * 2 * BCST + v;
            if (cb + 0 < BINS) zp[(cb + 0) * CST] = d.x;
            if (cb + 1 < BINS) zp[(cb + 1) * CST] = d.y;
            if (cb + 2 < BINS) zp[(cb + 2) * CST] = d.z;
            if (cb + 3 < BINS) zp[(cb + 3) * CST] = d.w;
        }
    }
    __syncthreads();

    // tail stages
    for (int s = 1; s <= TS; ++s) {
        const int half    = 1 << (s - 1);
        const int q       = l >> LCH;
        const int ch      = l & (NCH - 1);
        const int qp      = q & (half - 1);
        const int grpbase = (q >> (s - 1)) << s;
        const int vA = grpbase + qp, vB = vA + half, vo = grpbase + 2 * qp;
        #pragma unroll
        for (int ip = 0; ip < P4; ++ip) {
            const int pg = w * P4 + ip;
            const int p  = p_base + pg;
            float* zpg = zb + pg * 2 * BCST;
            const float* src = zpg + ((s & 1) ? 0 : BCST);
            float*       dst = zpg + ((s & 1) ? BCST : 0);
            const int shift = (qp + p * half) % BINS;
            for (int c = ch; c < BINS; c += NCH) {
                int sc0 = c - shift; if (sc0 < 0) sc0 += BINS;
                int sc1 = sc0 - 1;   if (sc1 < 0) sc1 += BINS;
                float a  = src[c * CST + vA];
                float b0 = src[sc0 * CST + vB];
                float b1 = src[sc1 * CST + vB];
                float2 o; o.x = a + b0; o.y = a + b1;
                *reinterpret_cast<float2*>(&dst[c * CST + vo]) = o;
            }
        }
        __syncthreads();
    }

    // full-lane stats: 256 rows per block, 1 per thread; contiguous out store
    {
        const int pg = t >> TS;
        const int v  = t & (M - 1);
        const float* z = zb + pg * 2 * BCST + ((TS & 1) ? BCST : 0);
        float a[BINS];
        #pragma unroll
        for (int c = 0; c < BINS; ++c) a[c] = z[c * CST + v];
        float mx = a[0];
        #pragma unroll
        for (int c = 1; c < BINS; ++c) mx = fmaxf(mx, a[c]);
        constexpr int MIDX = (BINS - 1) / 2;
        #pragma unroll
        for (int i = 0; i <= MIDX; ++i) {
            #pragma unroll
            for (int j = i + 1; j < BINS; ++j) {
                float lo = fminf(a[i], a[j]);
                float hi = fmaxf(a[i], a[j]);
                a[i] = lo; a[j] = hi;
            }
        }
        const float snr = (mx - a[MIDX]) * rstd[sl] * rsqrtf((float)R);
        out[(size_t)sl * OUTROWS + OUTOFF + p_base * M + t] = snr;
    }
}

__global__ __launch_bounds__(256)
void passB_all(const float* __restrict__ scr, const float* __restrict__ rstd,
               float* __restrict__ out)
{
    __shared__ float zb[16 * 2 * 19 * 20];   // 48.64 KB (max over configs)
    const int b = blockIdx.x;
    if (b < 8192) {
        const int cfg = b >> 11, r = b & 2047, pb = r & 63, sl = r >> 6;
        const int p_base = pb * 8;
        switch (cfg) {
            case 0: passB_body<10, 14, 9, 12, 0>    (zb, scr + SCROFF[0], rstd, out, 13107, p_base, sl); break;
            case 1: passB_body<11, 14, 9, 12, 16384>(zb, scr + SCROFF[1], rstd, out, 11915, p_base, sl); break;
            case 2: passB_body<12, 14, 9, 12, 32768>(zb, scr + SCROFF[2], rstd, out, 10922, p_base, sl); break;
            default: passB_body<13, 14, 9, 16, 49152>(zb, scr + SCROFF[3], rstd, out, 10082, p_base, sl); break;
        }
    } else {
        const int b2 = b - 8192;
        const int cfg = b2 >> 9, r = b2 & 511, pb = r & 15, sl = r >> 4;
        const int p_base = pb * 16;
        switch (cfg) {
            case 0: passB_body<16, 12, 8, 16, 65536>(zb, scr + SCROFF[4], rstd, out, 4096, p_base, sl); break;
            case 1: passB_body<17, 12, 8, 20, 69632>(zb, scr + SCROFF[5], rstd, out, 3855, p_base, sl); break;
            case 2: passB_body<18, 12, 8, 20, 73728>(zb, scr + SCROFF[6], rstd, out, 3640, p_base, sl); break;
            default: passB_body<19, 12, 8, 20, 77824>(zb, scr + SCROFF[7], rstd, out, 3449, p_base, sl); break;
        }
    }
}

// ---------------- host ----------------
extern "C" void kernel_launch(void* const* d_in, const int* in_sizes, int n_in,
                              void* d_out, int out_size, void* d_ws, size_t ws_size,
                              hipStream_t stream)
{
    (void)in_sizes; (void)n_in; (void)out_size; (void)ws_size;
    const float* x = (const float*)d_in[0];
    float* out  = (float*)d_out;
    float* wsf  = (float*)d_ws;
    float*  rstd = wsf;                                  // 32 floats (64 reserved)
    float2* part = reinterpret_cast<float2*>(wsf + 64);  // 1024 float2
    float*  scr  = wsf + 2176;                           // 16B-aligned scratch (148.9 MB used)

    hipLaunchKernelGGL(std_partial, dim3(NSEQ, STDCH), dim3(256), 0, stream, x, part);
    hipLaunchKernelGGL(std_final, dim3(1), dim3(64), 0, stream, part, rstd);
    hipLaunchKernelGGL(passA_all, dim3(6144), dim3(256), 0, stream, x, scr);
    hipLaunchKernelGGL(passB_all, dim3(10240), dim3(256), 0, stream, scr, rstd, out);
}

// Round 4
// 164.961 us; speedup vs baseline: 2.2650x; 1.3132x over previous
//
#include <hip/hip_runtime.h>
#include <cmath>

// FFA regressor for MI355X — 3 dispatches: std_partial, passA_all, passB_all.
//   passA: blocks of G=2^S0 rows; coalesced float4 init (exact w=0.5 downsample),
//          stages 1..S0 ping-pong in LDS (column-major stride G), bf16 RNE writeout
//          to scratch [sl][v=blk][p=row][c]  (contiguous G*CPAD run per block).
//   passB: P=16 p-values per block; coalesced bf16 gather (contiguous P*CPAD runs),
//          tail stages S0+1..K in-place (read-regs/barrier/write), extra shift p*2^(s-1),
//          rstd folded in from partials, fused max/median/SNR, contiguous out store.

constexpr int NSEQ    = 32;
constexpr int NLEN    = 262144;
constexpr int OUTROWS = 81920;
constexpr int STDCH   = 32;

constexpr int cilog2(int v) { int r = 0; while (v > 1) { v >>= 1; ++r; } return r; }

// scratch offsets per config, in bf16 elements (sizes: 32 * 2^K * CPAD)
constexpr size_t SCROFF[8] = {0, 6291456, 12582912, 18874368,
                              27262976, 29360128, 31981568, 34603008};

__device__ __forceinline__ unsigned bf16rne(float f) {
    unsigned u = __float_as_uint(f);
    return (u + 0x7FFFu + ((u >> 16) & 1u)) >> 16;
}
__device__ __forceinline__ unsigned pk2(float lo, float hi) {
    return bf16rne(lo) | (bf16rne(hi) << 16);
}

// ---------------- std partials ----------------
__global__ __launch_bounds__(256)
void std_partial(const float* __restrict__ x, float2* __restrict__ part)
{
    const int seq = blockIdx.x, ch = blockIdx.y;
    constexpr int N4 = NLEN / 4 / STDCH;
    const float4* xp = reinterpret_cast<const float4*>(x + (size_t)seq * NLEN) + (size_t)ch * N4;
    float s = 0.f, s2 = 0.f;
    for (int i = threadIdx.x; i < N4; i += 256) {
        float4 v = xp[i];
        s  += (v.x + v.y) + (v.z + v.w);
        s2 += (v.x * v.x + v.y * v.y) + (v.z * v.z + v.w * v.w);
    }
    #pragma unroll
    for (int off = 32; off > 0; off >>= 1) {
        s  += __shfl_down(s, off, 64);
        s2 += __shfl_down(s2, off, 64);
    }
    __shared__ float2 ws[4];
    const int w = threadIdx.x >> 6, l = threadIdx.x & 63;
    if (l == 0) ws[w] = make_float2(s, s2);
    __syncthreads();
    if (threadIdx.x == 0) {
        float a = ws[0].x + ws[1].x + ws[2].x + ws[3].x;
        float b = ws[0].y + ws[1].y + ws[2].y + ws[3].y;
        part[seq * STDCH + ch] = make_float2(a, b);
    }
}

// ---------------- pass A ----------------
template<int DS, int BINS, int K, int S0, int CPAD>
__device__ __forceinline__
void passA_body(float* __restrict__ buf, const float* __restrict__ xs,
                unsigned short* __restrict__ scrC, int R, int blk, int sl)
{
    constexpr int G      = 1 << S0;
    constexpr int M      = 1 << (K - S0);
    constexpr int PAIRS  = G / 2;
    constexpr int CSPLIT = 512 / PAIRS;
    constexpr int H      = (BINS + CSPLIT - 1) / CSPLIT;
    const int t = threadIdx.x;
    float* b0 = buf;
    float* b1 = buf + BINS * G;

    const int fmax = max(0, min(G * BINS, R * BINS - blk * G * BINS));

    // coalesced init: block input is one contiguous x range
    if constexpr (DS == 2) {
        const float4* src4 = reinterpret_cast<const float4*>(xs + 2 * (size_t)blk * G * BINS);
        constexpr int NF4 = G * BINS / 2;
        for (int i = t; i < NF4; i += 512) {
            const int f0 = 2 * i;
            if (f0 < fmax) {
                float4 v = src4[i];
                int lr = f0 / BINS, c = f0 - lr * BINS;
                b0[c * G + lr] = 0.5f * (v.x + v.y);
                if (f0 + 1 < fmax) {
                    int c1 = c + 1, lr1 = lr;
                    if (c1 == BINS) { c1 = 0; ++lr1; }
                    b0[c1 * G + lr1] = 0.5f * (v.z + v.w);
                }
            }
        }
    } else {
        const float4* src4 = reinterpret_cast<const float4*>(xs + 4 * (size_t)blk * G * BINS);
        constexpr int NF4 = G * BINS;
        for (int i = t; i < NF4; i += 512) {
            if (i < fmax) {
                float4 v = src4[i];
                int lr = i / BINS, c = i - lr * BINS;
                b0[c * G + lr] = 0.5f * (v.y + v.z);
            }
        }
    }
    for (int f = fmax + t; f < G * BINS; f += 512) {
        int lr = f / BINS, c = f - lr * BINS;
        b0[c * G + lr] = 0.f;
    }
    __syncthreads();

    // stages 1..S0, ping-pong; thread = (pair-row, column-chunk)
    const int pr  = t & (PAIRS - 1);
    const int chi = t / PAIRS;
    const int c0  = chi * H;
    for (int s = 1; s <= S0; ++s) {
        const float* src = (s & 1) ? b0 : b1;
        float*       dst = (s & 1) ? b1 : b0;
        const int half    = 1 << (s - 1);
        const int qp      = pr & (half - 1);
        const int grpbase = (pr >> (s - 1)) << s;
        const int rA = grpbase + qp, rB = rA + half, ro = grpbase + 2 * qp;
        const int shift = qp % BINS;
        int sc = c0 - shift; if (sc < 0) sc += BINS;
        int scm1 = sc - 1;   if (scm1 < 0) scm1 += BINS;
        float bprev = src[scm1 * G + rB];
        #pragma unroll
        for (int i2 = 0; i2 < H; ++i2) {
            const int c = c0 + i2;
            if (c < BINS) {
                float a  = src[c * G + rA];
                float bc = src[sc * G + rB];
                float2 o; o.x = a + bc; o.y = a + bprev;
                *reinterpret_cast<float2*>(&dst[c * G + ro]) = o;
                bprev = bc;
                ++sc; if (sc == BINS) sc = 0;
            }
        }
        __syncthreads();
    }

    // bf16 writeout: contiguous G*CPAD run per block
    const float* fin = (S0 & 1) ? b1 : b0;
    if constexpr (G == 512) {
        const int lr = t;
        unsigned u[CPAD / 2];
        #pragma unroll
        for (int k = 0; k < CPAD / 2; ++k) {
            const int ca = 2 * k, cb = 2 * k + 1;
            float fa = (ca < BINS) ? fin[ca * G + lr] : 0.f;
            float fb = (cb < BINS) ? fin[cb * G + lr] : 0.f;
            u[k] = pk2(fa, fb);
        }
        unsigned short* dst = scrC + ((size_t)(sl * M + blk) * G + lr) * CPAD;
        if constexpr (CPAD == 12) {
            uint2* d2 = reinterpret_cast<uint2*>(dst);
            d2[0] = make_uint2(u[0], u[1]);
            d2[1] = make_uint2(u[2], u[3]);
            d2[2] = make_uint2(u[4], u[5]);
        } else {
            uint4* d4 = reinterpret_cast<uint4*>(dst);
            d4[0] = make_uint4(u[0], u[1], u[2], u[3]);
            d4[1] = make_uint4(u[4], u[5], u[6], u[7]);
        }
    } else {
        const int lr = t & 255, chh = t >> 8;     // 2 thread-halves per row
        constexpr int CH = CPAD / 2;
        unsigned u[CH / 2];
        #pragma unroll
        for (int k = 0; k < CH / 2; ++k) {
            const int ca = chh * CH + 2 * k, cb = ca + 1;
            float fa = (ca < BINS) ? fin[ca * G + lr] : 0.f;
            float fb = (cb < BINS) ? fin[cb * G + lr] : 0.f;
            u[k] = pk2(fa, fb);
        }
        unsigned short* dst = scrC + ((size_t)(sl * M + blk) * G + lr) * CPAD + chh * CH;
        if constexpr (CH == 8) {
            *reinterpret_cast<uint4*>(dst) = make_uint4(u[0], u[1], u[2], u[3]);
        } else {
            unsigned* d = reinterpret_cast<unsigned*>(dst);
            #pragma unroll
            for (int k = 0; k < CH / 2; ++k) d[k] = u[k];
        }
    }
}

__global__ __launch_bounds__(512, 6)
void passA_all(const float* __restrict__ x, unsigned short* __restrict__ scr)
{
    __shared__ float buf[2 * 13 * 512];
    const int b = blockIdx.x;
    if (b < 4096) {
        const int cfg = b >> 10, r = b & 1023, blk = r & 31, sl = r >> 5;
        const float* xs = x + (size_t)sl * NLEN;
        switch (cfg) {
            case 0: passA_body<2, 10, 14, 9, 12>(buf, xs, scr + SCROFF[0], 13107, blk, sl); break;
            case 1: passA_body<2, 11, 14, 9, 12>(buf, xs, scr + SCROFF[1], 11915, blk, sl); break;
            case 2: passA_body<2, 12, 14, 9, 12>(buf, xs, scr + SCROFF[2], 10922, blk, sl); break;
            default: passA_body<2, 13, 14, 9, 16>(buf, xs, scr + SCROFF[3], 10082, blk, sl); break;
        }
    } else {
        const int b2 = b - 4096;
        const int cfg = b2 >> 9, r = b2 & 511, blk = r & 15, sl = r >> 4;
        const float* xs = x + (size_t)sl * NLEN;
        switch (cfg) {
            case 0: passA_body<4, 16, 12, 8, 16>(buf, xs, scr + SCROFF[4], 4096, blk, sl); break;
            case 1: passA_body<4, 17, 12, 8, 20>(buf, xs, scr + SCROFF[5], 3855, blk, sl); break;
            case 2: passA_body<4, 18, 12, 8, 20>(buf, xs, scr + SCROFF[6], 3640, blk, sl); break;
            default: passA_body<4, 19, 12, 8, 20>(buf, xs, scr + SCROFF[7], 3449, blk, sl); break;
        }
    }
}

// ---------------- pass B ----------------
template<int BINS, int K, int S0, int CPAD, int OUTOFF>
__device__ __forceinline__
void passB_body(float* __restrict__ zb, float* __restrict__ s_red,
                const unsigned short* __restrict__ scrC, const float2* __restrict__ part,
                float* __restrict__ out, int R, int p_base, int sl)
{
    constexpr int G     = 1 << S0;
    constexpr int M     = 1 << (K - S0);
    constexpr int TS    = K - S0;
    constexpr int P     = 16;
    constexpr int CST   = M + 4;
    constexpr int BCST  = BINS * CST;
    constexpr int NCH   = 64 / M;                  // lanes per pair in 32-thread pg group
    constexpr int LNCH  = cilog2(NCH);
    constexpr int CEILB = (BINS + NCH - 1) / NCH;

    const int t = threadIdx.x;

    // rstd * rsqrt(R) from std partials (wave 0)
    if (t < 64) {
        float s = 0.f, s2 = 0.f;
        if (t < 32) { float2 pp = part[sl * STDCH + t]; s = pp.x; s2 = pp.y; }
        #pragma unroll
        for (int off = 16; off > 0; off >>= 1) {
            s  += __shfl_down(s, off, 64);
            s2 += __shfl_down(s2, off, 64);
        }
        if (t == 0) {
            const float n = (float)NLEN;
            s_red[0] = rsqrtf((s2 - s * s / n) / (n - 1.f)) * rsqrtf((float)R);
        }
    }

    // gather: contiguous P*CPAD bf16 runs per v, uint2 = 4 bf16
    {
        constexpr int RUN = P * CPAD / 4;
        constexpr int TOT = M * RUN;
        const unsigned short* base = scrC + (size_t)sl * M * G * CPAD + (size_t)p_base * CPAD;
        for (int i = t; i < TOT; i += 512) {
            const int v = i / RUN, r = i - v * RUN;
            const uint2 d = *reinterpret_cast<const uint2*>(base + (size_t)v * G * CPAD + 4 * r);
            const int e0 = 4 * r;
            const int pl = e0 / CPAD, c = e0 - pl * CPAD;
            float* zp = zb + pl * BCST + v;
            if (c + 0 < BINS) zp[(c + 0) * CST] = __uint_as_float(d.x << 16);
            if (c + 1 < BINS) zp[(c + 1) * CST] = __uint_as_float(d.x & 0xFFFF0000u);
            if (c + 2 < BINS) zp[(c + 2) * CST] = __uint_as_float(d.y << 16);
            if (c + 3 < BINS) zp[(c + 3) * CST] = __uint_as_float(d.y & 0xFFFF0000u);
        }
    }
    __syncthreads();

    // tail stages, in-place (read regs -> barrier -> write)
    const int sub = t & 31, pg = t >> 5;
    const int p = p_base + pg;
    float* zpg = zb + pg * BCST;
    for (int s = 1; s <= TS; ++s) {
        const int half = 1 << (s - 1);
        const int q  = sub >> LNCH;
        const int ch = sub & (NCH - 1);
        const int qp = q & (half - 1);
        const int grp = (q >> (s - 1)) << s;
        const int vA = grp + qp, vB = vA + half, vo = grp + 2 * qp;
        const int shift = (qp + p * half) % BINS;
        float ra[CEILB], rb0[CEILB], rb1[CEILB];
        #pragma unroll
        for (int i2 = 0; i2 < CEILB; ++i2) {
            const int c = ch + i2 * NCH;
            if (c < BINS) {
                int sc0 = c - shift; if (sc0 < 0) sc0 += BINS;
                int sc1 = sc0 - 1;   if (sc1 < 0) sc1 += BINS;
                ra[i2]  = zpg[c   * CST + vA];
                rb0[i2] = zpg[sc0 * CST + vB];
                rb1[i2] = zpg[sc1 * CST + vB];
            }
        }
        __syncthreads();
        #pragma unroll
        for (int i2 = 0; i2 < CEILB; ++i2) {
            const int c = ch + i2 * NCH;
            if (c < BINS) {
                float2 o; o.x = ra[i2] + rb0[i2]; o.y = ra[i2] + rb1[i2];
                *reinterpret_cast<float2*>(&zpg[c * CST + vo]) = o;
            }
        }
        __syncthreads();
    }

    // fused stats: P*M rows, one per thread; contiguous out store
    constexpr int ROWS = P * M;
    if (t < ROWS) {
        const int pg2 = t >> TS;
        const int v   = t & (M - 1);
        const float* z = zb + pg2 * BCST;
        float a[BINS];
        #pragma unroll
        for (int c = 0; c < BINS; ++c) a[c] = z[c * CST + v];
        float mx = a[0];
        #pragma unroll
        for (int c = 1; c < BINS; ++c) mx = fmaxf(mx, a[c]);
        constexpr int MIDX = (BINS - 1) / 2;
        #pragma unroll
        for (int i = 0; i <= MIDX; ++i) {
            #pragma unroll
            for (int j = i + 1; j < BINS; ++j) {
                float lo = fminf(a[i], a[j]);
                float hi = fmaxf(a[i], a[j]);
                a[i] = lo; a[j] = hi;
            }
        }
        out[(size_t)sl * OUTROWS + OUTOFF + (size_t)p_base * M + t] = (mx - a[MIDX]) * s_red[0];
    }
}

__global__ __launch_bounds__(512, 6)
void passB_all(const unsigned short* __restrict__ scr, const float2* __restrict__ part,
               float* __restrict__ out)
{
    __shared__ float zb[16 * 13 * 36];   // 29.95 KB (max over configs)
    __shared__ float s_red[1];
    const int b = blockIdx.x;
    if (b < 4096) {
        const int cfg = b >> 10, r = b & 1023, pb = r & 31, sl = r >> 5;
        const int p_base = pb * 16;
        switch (cfg) {
            case 0: passB_body<10, 14, 9, 12, 0>    (zb, s_red, scr + SCROFF[0], part, out, 13107, p_base, sl); break;
            case 1: passB_body<11, 14, 9, 12, 16384>(zb, s_red, scr + SCROFF[1], part, out, 11915, p_base, sl); break;
            case 2: passB_body<12, 14, 9, 12, 32768>(zb, s_red, scr + SCROFF[2], part, out, 10922, p_base, sl); break;
            default: passB_body<13, 14, 9, 16, 49152>(zb, s_red, scr + SCROFF[3], part, out, 10082, p_base, sl); break;
        }
    } else {
        const int b2 = b - 4096;
        const int cfg = b2 >> 9, r = b2 & 511, pb = r & 15, sl = r >> 4;
        const int p_base = pb * 16;
        switch (cfg) {
            case 0: passB_body<16, 12, 8, 16, 65536>(zb, s_red, scr + SCROFF[4], part, out, 4096, p_base, sl); break;
            case 1: passB_body<17, 12, 8, 20, 69632>(zb, s_red, scr + SCROFF[5], part, out, 3855, p_base, sl); break;
            case 2: passB_body<18, 12, 8, 20, 73728>(zb, s_red, scr + SCROFF[6], part, out, 3640, p_base, sl); break;
            default: passB_body<19, 12, 8, 20, 77824>(zb, s_red, scr + SCROFF[7], part, out, 3449, p_base, sl); break;
        }
    }
}

// ---------------- host ----------------
extern "C" void kernel_launch(void* const* d_in, const int* in_sizes, int n_in,
                              void* d_out, int out_size, void* d_ws, size_t ws_size,
                              hipStream_t stream)
{
    (void)in_sizes; (void)n_in; (void)out_size; (void)ws_size;
    const float* x = (const float*)d_in[0];
    float* out  = (float*)d_out;
    float* wsf  = (float*)d_ws;
    float2* part = reinterpret_cast<float2*>(wsf + 64);        // 1024 float2
    unsigned short* scr = reinterpret_cast<unsigned short*>(wsf + 2176);  // 74.5 MB used

    hipLaunchKernelGGL(std_partial, dim3(NSEQ, STDCH), dim3(256), 0, stream, x, part);
    hipLaunchKernelGGL(passA_all, dim3(6144), dim3(512), 0, stream, x, scr);
    hipLaunchKernelGGL(passB_all, dim3(6144), dim3(512), 0, stream, scr, part, out);
}

// Round 5
// 162.708 us; speedup vs baseline: 2.2963x; 1.0138x over previous
//
#include <hip/hip_runtime.h>
#include <cmath>

// FFA regressor for MI355X — 3 dispatches: std_partial, passA_all, passB_all.
// R5: fused double-butterfly stages. Per output quad {4q..4q+3}: 4 row reads
// (stage-1: one float4 read), 8 adds, 1 float4 write; barriers halved.
//   passA: ping-pong in LDS, 4 fused steps (+1 single stage for S0=9), bf16 writeout.
//   passB: in-place (reg-staged) fused tail stages with p-shift, fused stats.

constexpr int NSEQ    = 32;
constexpr int NLEN    = 262144;
constexpr int OUTROWS = 81920;
constexpr int STDCH   = 32;

constexpr int cilog2(int v) { int r = 0; while (v > 1) { v >>= 1; ++r; } return r; }

// scratch offsets per config, in bf16 elements (sizes: 32 * 2^K * CPAD)
constexpr size_t SCROFF[8] = {0, 6291456, 12582912, 18874368,
                              27262976, 29360128, 31981568, 34603008};

template<int B>
__device__ __forceinline__ int mb(int x) { return ((x % B) + B) % B; }

__device__ __forceinline__ unsigned bf16rne(float f) {
    unsigned u = __float_as_uint(f);
    return (u + 0x7FFFu + ((u >> 16) & 1u)) >> 16;
}
__device__ __forceinline__ unsigned pk2(float lo, float hi) {
    return bf16rne(lo) | (bf16rne(hi) << 16);
}

// ---------------- std partials ----------------
__global__ __launch_bounds__(256)
void std_partial(const float* __restrict__ x, float2* __restrict__ part)
{
    const int seq = blockIdx.x, ch = blockIdx.y;
    constexpr int N4 = NLEN / 4 / STDCH;
    const float4* xp = reinterpret_cast<const float4*>(x + (size_t)seq * NLEN) + (size_t)ch * N4;
    float s = 0.f, s2 = 0.f;
    for (int i = threadIdx.x; i < N4; i += 256) {
        float4 v = xp[i];
        s  += (v.x + v.y) + (v.z + v.w);
        s2 += (v.x * v.x + v.y * v.y) + (v.z * v.z + v.w * v.w);
    }
    #pragma unroll
    for (int off = 32; off > 0; off >>= 1) {
        s  += __shfl_down(s, off, 64);
        s2 += __shfl_down(s2, off, 64);
    }
    __shared__ float2 ws[4];
    const int w = threadIdx.x >> 6, l = threadIdx.x & 63;
    if (l == 0) ws[w] = make_float2(s, s2);
    __syncthreads();
    if (threadIdx.x == 0) {
        float a = ws[0].x + ws[1].x + ws[2].x + ws[3].x;
        float b = ws[0].y + ws[1].y + ws[2].y + ws[3].y;
        part[seq * STDCH + ch] = make_float2(a, b);
    }
}

// ---------------- pass A stage kernels (ping-pong) ----------------
// fused stages (s, s+1), generic scalar reads
template<int BINS, int G, int H, int LQ>
__device__ __forceinline__
void fusedA(const float* __restrict__ src, float* __restrict__ dst, int s)
{
    constexpr int QUADS = G / 4;
    const int t = threadIdx.x;
    const int Q   = t & (QUADS - 1);
    const int chi = t >> LQ;
    const int c0  = chi * H;
    const int h = 1 << (s - 1), S = 1 << s;
    const int q  = Q & (h - 1);
    const int G2 = (Q >> (s - 1)) << (s + 1);
    const int rA0 = G2 + q, rA1 = rA0 + h, rB0 = G2 + S + q, rB1 = rB0 + h;
    const int vo = G2 + 4 * q;
    int ca = mb<BINS>(c0 - q), ga = mb<BINS>(c0 - 2 * q), cb = mb<BINS>(c0 - 3 * q);
    float a1p  = src[mb<BINS>(c0 - q - 1) * G + rA1];
    float b1p  = src[mb<BINS>(c0 - 3 * q - 1) * G + rB1];
    float b0m1 = src[mb<BINS>(c0 - 2 * q - 1) * G + rB0];
    float b0m2 = src[mb<BINS>(c0 - 2 * q - 2) * G + rB0];
    float b1m2 = src[mb<BINS>(c0 - 3 * q - 2) * G + rB1];
    float b1m3 = src[mb<BINS>(c0 - 3 * q - 3) * G + rB1];
    float v0p = b0m1 + b1p, v1p = b0m1 + b1m2, v1pp = b0m2 + b1m3;
    #pragma unroll
    for (int i2 = 0; i2 < H; ++i2) {
        const int c = c0 + i2;
        if (c < BINS) {
            float a0 = src[c * G + rA0];
            float a1 = src[ca * G + rA1];
            float b0 = src[ga * G + rB0];
            float b1 = src[cb * G + rB1];
            float u0 = a0 + a1, u1 = a0 + a1p;
            float v0 = b0 + b1, v1 = b0 + b1p;
            float4 o; o.x = u0 + v0; o.y = u0 + v0p; o.z = u1 + v1p; o.w = u1 + v1pp;
            *reinterpret_cast<float4*>(&dst[c * G + vo]) = o;
            a1p = a1; b1p = b1; v1pp = v1p; v1p = v1; v0p = v0;
            ++ca; if (ca == BINS) ca = 0;
            ++ga; if (ga == BINS) ga = 0;
            ++cb; if (cb == BINS) cb = 0;
        }
    }
}

// fused stages (1,2): 4 source rows contiguous -> float4 reads
template<int BINS, int G, int H, int LQ>
__device__ __forceinline__
void fusedA1(const float* __restrict__ src, float* __restrict__ dst)
{
    constexpr int QUADS = G / 4;
    const int t = threadIdx.x;
    const int Q   = t & (QUADS - 1);
    const int chi = t >> LQ;
    const int c0  = chi * H;
    const int r4  = 4 * Q;
    float4 fm1 = *reinterpret_cast<const float4*>(&src[mb<BINS>(c0 - 1) * G + r4]);
    float4 fm2 = *reinterpret_cast<const float4*>(&src[mb<BINS>(c0 - 2) * G + r4]);
    float4 fm3 = *reinterpret_cast<const float4*>(&src[mb<BINS>(c0 - 3) * G + r4]);
    float a1p = fm1.y, b1p = fm1.w;
    float v0p  = fm1.z + fm1.w;
    float v1p  = fm1.z + fm2.w;
    float v1pp = fm2.z + fm3.w;
    #pragma unroll
    for (int i2 = 0; i2 < H; ++i2) {
        const int c = c0 + i2;
        if (c < BINS) {
            float4 f = *reinterpret_cast<const float4*>(&src[c * G + r4]);
            float u0 = f.x + f.y, u1 = f.x + a1p;
            float v0 = f.z + f.w, v1 = f.z + b1p;
            float4 o; o.x = u0 + v0; o.y = u0 + v0p; o.z = u1 + v1p; o.w = u1 + v1pp;
            *reinterpret_cast<float4*>(&dst[c * G + r4]) = o;
            a1p = f.y; b1p = f.w; v1pp = v1p; v1p = v1; v0p = v0;
        }
    }
}

// single stage (rolling), used for stage S0=9
template<int BINS, int G, int H1, int LP>
__device__ __forceinline__
void singleA(const float* __restrict__ src, float* __restrict__ dst, int s)
{
    constexpr int PAIRS = G / 2;
    const int t = threadIdx.x;
    const int pr  = t & (PAIRS - 1);
    const int chi = t >> LP;
    const int c0  = chi * H1;
    const int half = 1 << (s - 1);
    const int qp = pr & (half - 1);
    const int grpbase = (pr >> (s - 1)) << s;
    const int rA = grpbase + qp, rB = rA + half, ro = grpbase + 2 * qp;
    const int shift = qp % BINS;
    int sc = mb<BINS>(c0 - shift);
    float bprev = src[mb<BINS>(c0 - shift - 1) * G + rB];
    #pragma unroll
    for (int i2 = 0; i2 < H1; ++i2) {
        const int c = c0 + i2;
        if (c < BINS) {
            float a  = src[c * G + rA];
            float bc = src[sc * G + rB];
            float2 o; o.x = a + bc; o.y = a + bprev;
            *reinterpret_cast<float2*>(&dst[c * G + ro]) = o;
            bprev = bc;
            ++sc; if (sc == BINS) sc = 0;
        }
    }
}

// ---------------- pass A body ----------------
template<int DS, int BINS, int K, int S0, int CPAD>
__device__ __forceinline__
void passA_body(float* __restrict__ buf, const float* __restrict__ xs,
                unsigned short* __restrict__ scrC, int R, int blk, int sl)
{
    constexpr int G      = 1 << S0;
    constexpr int M      = 1 << (K - S0);
    constexpr int QUADS  = G / 4;
    constexpr int LQ     = cilog2(QUADS);
    constexpr int CSPLIT = 512 / QUADS;
    constexpr int H      = (BINS + CSPLIT - 1) / CSPLIT;
    constexpr int PAIRS  = G / 2;
    constexpr int LP     = cilog2(PAIRS);
    constexpr int CS1    = 512 / PAIRS;
    constexpr int H1     = (BINS + CS1 - 1) / CS1;
    const int t = threadIdx.x;
    float* b0 = buf;
    float* b1 = buf + BINS * G;

    const int fmax = max(0, min(G * BINS, R * BINS - blk * G * BINS));

    // coalesced init: block input is one contiguous x range
    if constexpr (DS == 2) {
        const float4* src4 = reinterpret_cast<const float4*>(xs + 2 * (size_t)blk * G * BINS);
        constexpr int NF4 = G * BINS / 2;
        for (int i = t; i < NF4; i += 512) {
            const int f0 = 2 * i;
            if (f0 < fmax) {
                float4 v = src4[i];
                int lr = f0 / BINS, c = f0 - lr * BINS;
                b0[c * G + lr] = 0.5f * (v.x + v.y);
                if (f0 + 1 < fmax) {
                    int c1 = c + 1, lr1 = lr;
                    if (c1 == BINS) { c1 = 0; ++lr1; }
                    b0[c1 * G + lr1] = 0.5f * (v.z + v.w);
                }
            }
        }
    } else {
        const float4* src4 = reinterpret_cast<const float4*>(xs + 4 * (size_t)blk * G * BINS);
        constexpr int NF4 = G * BINS;
        for (int i = t; i < NF4; i += 512) {
            if (i < fmax) {
                float4 v = src4[i];
                int lr = i / BINS, c = i - lr * BINS;
                b0[c * G + lr] = 0.5f * (v.y + v.z);
            }
        }
    }
    for (int f = fmax + t; f < G * BINS; f += 512) {
        int lr = f / BINS, c = f - lr * BINS;
        b0[c * G + lr] = 0.f;
    }
    __syncthreads();

    // fused stages
    fusedA1<BINS, G, H, LQ>(b0, b1);    __syncthreads();
    fusedA <BINS, G, H, LQ>(b1, b0, 3); __syncthreads();
    fusedA <BINS, G, H, LQ>(b0, b1, 5); __syncthreads();
    fusedA <BINS, G, H, LQ>(b1, b0, 7); __syncthreads();
    if constexpr (S0 == 9) {
        singleA<BINS, G, H1, LP>(b0, b1, 9); __syncthreads();
    }

    // bf16 writeout: contiguous G*CPAD run per block
    const float* fin = (S0 & 1) ? b1 : b0;
    if constexpr (G == 512) {
        const int lr = t;
        unsigned u[CPAD / 2];
        #pragma unroll
        for (int k = 0; k < CPAD / 2; ++k) {
            const int ca = 2 * k, cbn = 2 * k + 1;
            float fa = (ca < BINS)  ? fin[ca * G + lr]  : 0.f;
            float fb = (cbn < BINS) ? fin[cbn * G + lr] : 0.f;
            u[k] = pk2(fa, fb);
        }
        unsigned short* dst = scrC + ((size_t)(sl * M + blk) * G + lr) * CPAD;
        if constexpr (CPAD == 12) {
            uint2* d2 = reinterpret_cast<uint2*>(dst);
            d2[0] = make_uint2(u[0], u[1]);
            d2[1] = make_uint2(u[2], u[3]);
            d2[2] = make_uint2(u[4], u[5]);
        } else {
            uint4* d4 = reinterpret_cast<uint4*>(dst);
            d4[0] = make_uint4(u[0], u[1], u[2], u[3]);
            d4[1] = make_uint4(u[4], u[5], u[6], u[7]);
        }
    } else {
        const int lr = t & 255, chh = t >> 8;     // 2 thread-halves per row
        constexpr int CH = CPAD / 2;
        unsigned u[CH / 2];
        #pragma unroll
        for (int k = 0; k < CH / 2; ++k) {
            const int ca = chh * CH + 2 * k, cbn = ca + 1;
            float fa = (ca < BINS)  ? fin[ca * G + lr]  : 0.f;
            float fb = (cbn < BINS) ? fin[cbn * G + lr] : 0.f;
            u[k] = pk2(fa, fb);
        }
        unsigned short* dst = scrC + ((size_t)(sl * M + blk) * G + lr) * CPAD + chh * CH;
        if constexpr (CH == 8) {
            *reinterpret_cast<uint4*>(dst) = make_uint4(u[0], u[1], u[2], u[3]);
        } else {
            unsigned* d = reinterpret_cast<unsigned*>(dst);
            #pragma unroll
            for (int k = 0; k < CH / 2; ++k) d[k] = u[k];
        }
    }
}

__global__ __launch_bounds__(512, 6)
void passA_all(const float* __restrict__ x, unsigned short* __restrict__ scr)
{
    __shared__ float buf[2 * 13 * 512];
    const int b = blockIdx.x;
    if (b < 4096) {
        const int cfg = b >> 10, r = b & 1023, blk = r & 31, sl = r >> 5;
        const float* xs = x + (size_t)sl * NLEN;
        switch (cfg) {
            case 0: passA_body<2, 10, 14, 9, 12>(buf, xs, scr + SCROFF[0], 13107, blk, sl); break;
            case 1: passA_body<2, 11, 14, 9, 12>(buf, xs, scr + SCROFF[1], 11915, blk, sl); break;
            case 2: passA_body<2, 12, 14, 9, 12>(buf, xs, scr + SCROFF[2], 10922, blk, sl); break;
            default: passA_body<2, 13, 14, 9, 16>(buf, xs, scr + SCROFF[3], 10082, blk, sl); break;
        }
    } else {
        const int b2 = b - 4096;
        const int cfg = b2 >> 9, r = b2 & 511, blk = r & 15, sl = r >> 4;
        const float* xs = x + (size_t)sl * NLEN;
        switch (cfg) {
            case 0: passA_body<4, 16, 12, 8, 16>(buf, xs, scr + SCROFF[4], 4096, blk, sl); break;
            case 1: passA_body<4, 17, 12, 8, 20>(buf, xs, scr + SCROFF[5], 3855, blk, sl); break;
            case 2: passA_body<4, 18, 12, 8, 20>(buf, xs, scr + SCROFF[6], 3640, blk, sl); break;
            default: passA_body<4, 19, 12, 8, 20>(buf, xs, scr + SCROFF[7], 3449, blk, sl); break;
        }
    }
}

// ---------------- pass B stage kernels (in-place, reg-staged) ----------------
template<int BINS, int M, int CST, int HB, int LQ>
__device__ __forceinline__
void fusedB(float* __restrict__ zpg, int s, int p, int sub)
{
    constexpr int QUADS = M / 4;
    const int Q   = sub & (QUADS - 1);
    const int chi = sub >> LQ;
    const int c0  = chi * HB;
    const int h = 1 << (s - 1), S = 1 << s;
    const int q  = Q & (h - 1);
    const int G2 = (Q >> (s - 1)) << (s + 1);
    const int rA0 = G2 + q, rA1 = rA0 + h, rB0 = G2 + S + q, rB1 = rB0 + h;
    const int vo = G2 + 4 * q;
    const int ba1 = mb<BINS>(c0 - q - p * h - 1);
    const int bb0 = mb<BINS>(c0 - 2 * q - p * S - 2);
    const int bb1 = mb<BINS>(c0 - 3 * q - p * (S + h) - 3);

    float fa0[HB], fa1[HB + 1], fb0[HB + 2], fb1[HB + 3];
    #pragma unroll
    for (int i = 0; i < HB; ++i) {
        int cc = c0 + i; if (cc >= BINS) cc = BINS - 1;
        fa0[i] = zpg[cc * CST + rA0];
    }
    int idx = ba1;
    #pragma unroll
    for (int i = 0; i < HB + 1; ++i) {
        fa1[i] = zpg[idx * CST + rA1];
        ++idx; if (idx == BINS) idx = 0;
    }
    idx = bb0;
    #pragma unroll
    for (int i = 0; i < HB + 2; ++i) {
        fb0[i] = zpg[idx * CST + rB0];
        ++idx; if (idx == BINS) idx = 0;
    }
    idx = bb1;
    #pragma unroll
    for (int i = 0; i < HB + 3; ++i) {
        fb1[i] = zpg[idx * CST + rB1];
        ++idx; if (idx == BINS) idx = 0;
    }
    __syncthreads();
    #pragma unroll
    for (int i2 = 0; i2 < HB; ++i2) {
        const int c = c0 + i2;
        if (c < BINS) {
            float u0 = fa0[i2] + fa1[i2 + 1];
            float u1 = fa0[i2] + fa1[i2];
            float v0c  = fb0[i2 + 2] + fb1[i2 + 3];
            float v0p  = fb0[i2 + 1] + fb1[i2 + 2];
            float v1p  = fb0[i2 + 1] + fb1[i2 + 1];
            float v1pp = fb0[i2]     + fb1[i2];
            float4 o; o.x = u0 + v0c; o.y = u0 + v0p; o.z = u1 + v1p; o.w = u1 + v1pp;
            *reinterpret_cast<float4*>(&zpg[c * CST + vo]) = o;
        }
    }
    __syncthreads();
}

template<int BINS, int M, int CST, int HSB, int LP>
__device__ __forceinline__
void singleB(float* __restrict__ zpg, int s, int p, int sub)
{
    constexpr int PAIRSB = M / 2;
    const int pr  = sub & (PAIRSB - 1);
    const int chi = sub >> LP;
    const int c0  = chi * HSB;
    const int half = 1 << (s - 1);
    const int qp = pr & (half - 1);
    const int grpbase = (pr >> (s - 1)) << s;
    const int rA = grpbase + qp, rB = rA + half, ro = grpbase + 2 * qp;
    const int shift = (qp + p * half) % BINS;

    float ra[HSB], rb[HSB + 1];
    #pragma unroll
    for (int i = 0; i < HSB; ++i) {
        int cc = c0 + i; if (cc >= BINS) cc = BINS - 1;
        ra[i] = zpg[cc * CST + rA];
    }
    int idx = mb<BINS>(c0 - shift - 1);
    #pragma unroll
    for (int i = 0; i < HSB + 1; ++i) {
        rb[i] = zpg[idx * CST + rB];
        ++idx; if (idx == BINS) idx = 0;
    }
    __syncthreads();
    #pragma unroll
    for (int i2 = 0; i2 < HSB; ++i2) {
        const int c = c0 + i2;
        if (c < BINS) {
            float2 o; o.x = ra[i2] + rb[i2 + 1]; o.y = ra[i2] + rb[i2];
            *reinterpret_cast<float2*>(&zpg[c * CST + ro]) = o;
        }
    }
    __syncthreads();
}

// ---------------- pass B body ----------------
template<int BINS, int K, int S0, int CPAD, int OUTOFF>
__device__ __forceinline__
void passB_body(float* __restrict__ zb, float* __restrict__ s_red,
                const unsigned short* __restrict__ scrC, const float2* __restrict__ part,
                float* __restrict__ out, int R, int p_base, int sl)
{
    constexpr int G    = 1 << S0;
    constexpr int M    = 1 << (K - S0);
    constexpr int TS   = K - S0;
    constexpr int P    = 16;
    constexpr int CST  = M + 4;
    constexpr int BCST = BINS * CST;
    constexpr int LQB  = cilog2(M / 4);
    constexpr int CHB  = 32 / (M / 4);
    constexpr int HB   = (BINS + CHB - 1) / CHB;
    constexpr int LPB  = cilog2(M / 2);
    constexpr int CSB  = 32 / (M / 2);
    constexpr int HSB  = (BINS + CSB - 1) / CSB;

    const int t = threadIdx.x;

    // rstd * rsqrt(R) from std partials (wave 0)
    if (t < 64) {
        float s = 0.f, s2 = 0.f;
        if (t < 32) { float2 pp = part[sl * STDCH + t]; s = pp.x; s2 = pp.y; }
        #pragma unroll
        for (int off = 16; off > 0; off >>= 1) {
            s  += __shfl_down(s, off, 64);
            s2 += __shfl_down(s2, off, 64);
        }
        if (t == 0) {
            const float n = (float)NLEN;
            s_red[0] = rsqrtf((s2 - s * s / n) / (n - 1.f)) * rsqrtf((float)R);
        }
    }

    // gather: contiguous P*CPAD bf16 runs per v, uint2 = 4 bf16
    {
        constexpr int RUN = P * CPAD / 4;
        constexpr int TOT = M * RUN;
        const unsigned short* base = scrC + (size_t)sl * M * G * CPAD + (size_t)p_base * CPAD;
        for (int i = t; i < TOT; i += 512) {
            const int v = i / RUN, r = i - v * RUN;
            const uint2 d = *reinterpret_cast<const uint2*>(base + (size_t)v * G * CPAD + 4 * r);
            const int e0 = 4 * r;
            const int pl = e0 / CPAD, c = e0 - pl * CPAD;
            float* zp = zb + pl * BCST + v;
            if (c + 0 < BINS) zp[(c + 0) * CST] = __uint_as_float(d.x << 16);
            if (c + 1 < BINS) zp[(c + 1) * CST] = __uint_as_float(d.x & 0xFFFF0000u);
            if (c + 2 < BINS) zp[(c + 2) * CST] = __uint_as_float(d.y << 16);
            if (c + 3 < BINS) zp[(c + 3) * CST] = __uint_as_float(d.y & 0xFFFF0000u);
        }
    }
    __syncthreads();

    // tail stages (fused, in-place)
    const int sub = t & 31, pg = t >> 5;
    const int p = p_base + pg;
    float* zpg = zb + pg * BCST;
    fusedB<BINS, M, CST, HB, LQB>(zpg, 1, p, sub);
    fusedB<BINS, M, CST, HB, LQB>(zpg, 3, p, sub);
    if constexpr (TS == 5) {
        singleB<BINS, M, CST, HSB, LPB>(zpg, 5, p, sub);
    }

    // fused stats: P*M rows, one per thread; contiguous out store
    constexpr int ROWS = P * M;
    if (t < ROWS) {
        const int pg2 = t >> TS;
        const int v   = t & (M - 1);
        const float* z = zb + pg2 * BCST;
        float a[BINS];
        #pragma unroll
        for (int c = 0; c < BINS; ++c) a[c] = z[c * CST + v];
        float mx = a[0];
        #pragma unroll
        for (int c = 1; c < BINS; ++c) mx = fmaxf(mx, a[c]);
        constexpr int MIDX = (BINS - 1) / 2;
        #pragma unroll
        for (int i = 0; i <= MIDX; ++i) {
            #pragma unroll
            for (int j = i + 1; j < BINS; ++j) {
                float lo = fminf(a[i], a[j]);
                float hi = fmaxf(a[i], a[j]);
                a[i] = lo; a[j] = hi;
            }
        }
        out[(size_t)sl * OUTROWS + OUTOFF + (size_t)p_base * M + t] = (mx - a[MIDX]) * s_red[0];
    }
}

__global__ __launch_bounds__(512, 6)
void passB_all(const unsigned short* __restrict__ scr, const float2* __restrict__ part,
               float* __restrict__ out)
{
    __shared__ float zb[16 * 13 * 36];   // 29.95 KB (max over configs)
    __shared__ float s_red[1];
    const int b = blockIdx.x;
    if (b < 4096) {
        const int cfg = b >> 10, r = b & 1023, pb = r & 31, sl = r >> 5;
        const int p_base = pb * 16;
        switch (cfg) {
            case 0: passB_body<10, 14, 9, 12, 0>    (zb, s_red, scr + SCROFF[0], part, out, 13107, p_base, sl); break;
            case 1: passB_body<11, 14, 9, 12, 16384>(zb, s_red, scr + SCROFF[1], part, out, 11915, p_base, sl); break;
            case 2: passB_body<12, 14, 9, 12, 32768>(zb, s_red, scr + SCROFF[2], part, out, 10922, p_base, sl); break;
            default: passB_body<13, 14, 9, 16, 49152>(zb, s_red, scr + SCROFF[3], part, out, 10082, p_base, sl); break;
        }
    } else {
        const int b2 = b - 4096;
        const int cfg = b2 >> 9, r = b2 & 511, pb = r & 15, sl = r >> 4;
        const int p_base = pb * 16;
        switch (cfg) {
            case 0: passB_body<16, 12, 8, 16, 65536>(zb, s_red, scr + SCROFF[4], part, out, 4096, p_base, sl); break;
            case 1: passB_body<17, 12, 8, 20, 69632>(zb, s_red, scr + SCROFF[5], part, out, 3855, p_base, sl); break;
            case 2: passB_body<18, 12, 8, 20, 73728>(zb, s_red, scr + SCROFF[6], part, out, 3640, p_base, sl); break;
            default: passB_body<19, 12, 8, 20, 77824>(zb, s_red, scr + SCROFF[7], part, out, 3449, p_base, sl); break;
        }
    }
}

// ---------------- host ----------------
extern "C" void kernel_launch(void* const* d_in, const int* in_sizes, int n_in,
                              void* d_out, int out_size, void* d_ws, size_t ws_size,
                              hipStream_t stream)
{
    (void)in_sizes; (void)n_in; (void)out_size; (void)ws_size;
    const float* x = (const float*)d_in[0];
    float* out  = (float*)d_out;
    float* wsf  = (float*)d_ws;
    float2* part = reinterpret_cast<float2*>(wsf + 64);        // 1024 float2
    unsigned short* scr = reinterpret_cast<unsigned short*>(wsf + 2176);  // 74.5 MB used

    hipLaunchKernelGGL(std_partial, dim3(NSEQ, STDCH), dim3(256), 0, stream, x, part);
    hipLaunchKernelGGL(passA_all, dim3(6144), dim3(512), 0, stream, x, scr);
    hipLaunchKernelGGL(passB_all, dim3(6144), dim3(512), 0, stream, scr, part, out);
}

// Round 7
// 156.580 us; speedup vs baseline: 2.3862x; 1.0391x over previous
//
#include <hip/hip_runtime.h>
#include <cmath>

// FFA regressor for MI355X — 3 dispatches: std_partial, passA_all, passB_all.
// R7: passA reverted to the proven R4 single-stage structure, made IN-PLACE
// (read window to regs -> barrier -> write -> barrier; same pattern as passB's
// singleB, proven since R4). Single buffer, CST=G+4: LDS 53248->26832 B, so
// occupancy goes 3 blocks/CU (24 waves) -> 4 blocks/CU (32 waves, wave-capped).
// passB and std unchanged from R5 (passed, passB ~29us).

constexpr int NSEQ    = 32;
constexpr int NLEN    = 262144;
constexpr int OUTROWS = 81920;
constexpr int STDCH   = 32;

constexpr int cilog2(int v) { int r = 0; while (v > 1) { v >>= 1; ++r; } return r; }

// scratch offsets per config, in bf16 elements (sizes: 32 * 2^K * CPAD)
constexpr size_t SCROFF[8] = {0, 6291456, 12582912, 18874368,
                              27262976, 29360128, 31981568, 34603008};

__device__ __forceinline__ unsigned bf16rne(float f) {
    unsigned u = __float_as_uint(f);
    return (u + 0x7FFFu + ((u >> 16) & 1u)) >> 16;
}
__device__ __forceinline__ unsigned pk2(float lo, float hi) {
    return bf16rne(lo) | (bf16rne(hi) << 16);
}

// ---------------- std partials ----------------
__global__ __launch_bounds__(256)
void std_partial(const float* __restrict__ x, float2* __restrict__ part)
{
    const int seq = blockIdx.x, ch = blockIdx.y;
    constexpr int N4 = NLEN / 4 / STDCH;
    const float4* xp = reinterpret_cast<const float4*>(x + (size_t)seq * NLEN) + (size_t)ch * N4;
    float s = 0.f, s2 = 0.f;
    for (int i = threadIdx.x; i < N4; i += 256) {
        float4 v = xp[i];
        s  += (v.x + v.y) + (v.z + v.w);
        s2 += (v.x * v.x + v.y * v.y) + (v.z * v.z + v.w * v.w);
    }
    #pragma unroll
    for (int off = 32; off > 0; off >>= 1) {
        s  += __shfl_down(s, off, 64);
        s2 += __shfl_down(s2, off, 64);
    }
    __shared__ float2 ws[4];
    const int w = threadIdx.x >> 6, l = threadIdx.x & 63;
    if (l == 0) ws[w] = make_float2(s, s2);
    __syncthreads();
    if (threadIdx.x == 0) {
        float a = ws[0].x + ws[1].x + ws[2].x + ws[3].x;
        float b = ws[0].y + ws[1].y + ws[2].y + ws[3].y;
        part[seq * STDCH + ch] = make_float2(a, b);
    }
}

// ---------------- pass A: in-place single stage ----------------
template<int BINS, int G, int H1, int LP>
__device__ __forceinline__
void stageIP(float* __restrict__ buf, int s)
{
    constexpr int CST = G + 4;
    constexpr int PAIRS = G / 2;
    const int t = threadIdx.x;
    const int pr  = t & (PAIRS - 1);
    const int chi = t >> LP;
    const int c0  = chi * H1;            // always < BINS for our configs
    const int half = 1 << (s - 1);
    const int qp = pr & (half - 1);
    const int grpbase = (pr >> (s - 1)) << s;
    const int rA = grpbase + qp, rB = rA + half, ro = grpbase + 2 * qp;
    const int shift = qp % BINS;

    float ra[H1], rb[H1 + 1];
    #pragma unroll
    for (int i = 0; i < H1; ++i) {
        int cc = c0 + i; if (cc >= BINS) cc = BINS - 1;
        ra[i] = buf[cc * CST + rA];
    }
    int idx = c0 - shift - 1; if (idx < 0) idx += BINS;
    #pragma unroll
    for (int i = 0; i < H1 + 1; ++i) {
        rb[i] = buf[idx * CST + rB];
        ++idx; if (idx == BINS) idx = 0;
    }
    __syncthreads();
    #pragma unroll
    for (int i = 0; i < H1; ++i) {
        const int c = c0 + i;
        if (c < BINS) {
            float2 o; o.x = ra[i] + rb[i + 1]; o.y = ra[i] + rb[i];
            *reinterpret_cast<float2*>(&buf[c * CST + ro]) = o;
        }
    }
    __syncthreads();
}

// ---------------- pass A body ----------------
template<int DS, int BINS, int K, int S0, int CPAD>
__device__ __forceinline__
void passA_body(float* __restrict__ buf, const float* __restrict__ xs,
                unsigned short* __restrict__ scrC, int R, int blk, int sl)
{
    constexpr int G     = 1 << S0;
    constexpr int M     = 1 << (K - S0);
    constexpr int CST   = G + 4;
    constexpr int PAIRS = G / 2;
    constexpr int LP    = cilog2(PAIRS);
    constexpr int CS1   = 512 / PAIRS;
    constexpr int H1    = (BINS + CS1 - 1) / CS1;
    const int t = threadIdx.x;

    const int fmax = max(0, min(G * BINS, R * BINS - blk * G * BINS));

    // coalesced init: block input is one contiguous x range (exact w=0.5 downsample)
    if constexpr (DS == 2) {
        const float4* src4 = reinterpret_cast<const float4*>(xs + 2 * (size_t)blk * G * BINS);
        constexpr int NF4 = G * BINS / 2;
        for (int i = t; i < NF4; i += 512) {
            const int f0 = 2 * i;
            if (f0 < fmax) {
                float4 v = src4[i];
                int lr = f0 / BINS, c = f0 - lr * BINS;
                buf[c * CST + lr] = 0.5f * (v.x + v.y);
                if (f0 + 1 < fmax) {
                    int c1 = c + 1, lr1 = lr;
                    if (c1 == BINS) { c1 = 0; ++lr1; }
                    buf[c1 * CST + lr1] = 0.5f * (v.z + v.w);
                }
            }
        }
    } else {
        const float4* src4 = reinterpret_cast<const float4*>(xs + 4 * (size_t)blk * G * BINS);
        constexpr int NF4 = G * BINS;
        for (int i = t; i < NF4; i += 512) {
            if (i < fmax) {
                float4 v = src4[i];
                int lr = i / BINS, c = i - lr * BINS;
                buf[c * CST + lr] = 0.5f * (v.y + v.z);
            }
        }
    }
    for (int f = fmax + t; f < G * BINS; f += 512) {
        int lr = f / BINS, c = f - lr * BINS;
        buf[c * CST + lr] = 0.f;
    }
    __syncthreads();

    // stages 1..S0, in-place
    for (int s = 1; s <= S0; ++s)
        stageIP<BINS, G, H1, LP>(buf, s);

    // bf16 writeout: contiguous G*CPAD run per block
    const float* fin = buf;
    if constexpr (G == 512) {
        const int lr = t;
        unsigned u[CPAD / 2];
        #pragma unroll
        for (int k = 0; k < CPAD / 2; ++k) {
            const int ca = 2 * k, cbn = 2 * k + 1;
            float fa = (ca < BINS)  ? fin[ca * CST + lr]  : 0.f;
            float fb = (cbn < BINS) ? fin[cbn * CST + lr] : 0.f;
            u[k] = pk2(fa, fb);
        }
        unsigned short* dst = scrC + ((size_t)(sl * M + blk) * G + lr) * CPAD;
        if constexpr (CPAD == 12) {
            uint2* d2 = reinterpret_cast<uint2*>(dst);
            d2[0] = make_uint2(u[0], u[1]);
            d2[1] = make_uint2(u[2], u[3]);
            d2[2] = make_uint2(u[4], u[5]);
        } else {
            uint4* d4 = reinterpret_cast<uint4*>(dst);
            d4[0] = make_uint4(u[0], u[1], u[2], u[3]);
            d4[1] = make_uint4(u[4], u[5], u[6], u[7]);
        }
    } else {
        const int lr = t & 255, chh = t >> 8;     // 2 thread-halves per row
        constexpr int CH = CPAD / 2;
        unsigned u[CH / 2];
        #pragma unroll
        for (int k = 0; k < CH / 2; ++k) {
            const int ca = chh * CH + 2 * k, cbn = ca + 1;
            float fa = (ca < BINS)  ? fin[ca * CST + lr]  : 0.f;
            float fb = (cbn < BINS) ? fin[cbn * CST + lr] : 0.f;
            u[k] = pk2(fa, fb);
        }
        unsigned short* dst = scrC + ((size_t)(sl * M + blk) * G + lr) * CPAD + chh * CH;
        if constexpr (CH == 8) {
            *reinterpret_cast<uint4*>(dst) = make_uint4(u[0], u[1], u[2], u[3]);
        } else {
            unsigned* d = reinterpret_cast<unsigned*>(dst);
            #pragma unroll
            for (int k = 0; k < CH / 2; ++k) d[k] = u[k];
        }
    }
}

__global__ __launch_bounds__(512, 8)
void passA_all(const float* __restrict__ x, unsigned short* __restrict__ scr)
{
    __shared__ float buf[13 * 516];   // 26,832 B: 4 blocks/CU (wave-capped)
    const int b = blockIdx.x;
    if (b < 4096) {
        const int cfg = b >> 10, r = b & 1023, blk = r & 31, sl = r >> 5;
        const float* xs = x + (size_t)sl * NLEN;
        switch (cfg) {
            case 0: passA_body<2, 10, 14, 9, 12>(buf, xs, scr + SCROFF[0], 13107, blk, sl); break;
            case 1: passA_body<2, 11, 14, 9, 12>(buf, xs, scr + SCROFF[1], 11915, blk, sl); break;
            case 2: passA_body<2, 12, 14, 9, 12>(buf, xs, scr + SCROFF[2], 10922, blk, sl); break;
            default: passA_body<2, 13, 14, 9, 16>(buf, xs, scr + SCROFF[3], 10082, blk, sl); break;
        }
    } else {
        const int b2 = b - 4096;
        const int cfg = b2 >> 9, r = b2 & 511, blk = r & 15, sl = r >> 4;
        const float* xs = x + (size_t)sl * NLEN;
        switch (cfg) {
            case 0: passA_body<4, 16, 12, 8, 16>(buf, xs, scr + SCROFF[4], 4096, blk, sl); break;
            case 1: passA_body<4, 17, 12, 8, 20>(buf, xs, scr + SCROFF[5], 3855, blk, sl); break;
            case 2: passA_body<4, 18, 12, 8, 20>(buf, xs, scr + SCROFF[6], 3640, blk, sl); break;
            default: passA_body<4, 19, 12, 8, 20>(buf, xs, scr + SCROFF[7], 3449, blk, sl); break;
        }
    }
}

// ---------------- pass B (unchanged from R5) ----------------
template<int BINS, int M, int CST, int HB, int LQ>
__device__ __forceinline__
void fusedB(float* __restrict__ zpg, int s, int p, int sub)
{
    constexpr int QUADS = M / 4;
    const int Q   = sub & (QUADS - 1);
    const int chi = sub >> LQ;
    const int c0  = chi * HB;
    const int h = 1 << (s - 1), S = 1 << s;
    const int q  = Q & (h - 1);
    const int G2 = (Q >> (s - 1)) << (s + 1);
    const int rA0 = G2 + q, rA1 = rA0 + h, rB0 = G2 + S + q, rB1 = rB0 + h;
    const int vo = G2 + 4 * q;
    auto mbf = [](int x, int B) { int r = x % B; return r < 0 ? r + B : r; };
    const int ba1 = mbf(c0 - q - p * h - 1, BINS);
    const int bb0 = mbf(c0 - 2 * q - p * S - 2, BINS);
    const int bb1 = mbf(c0 - 3 * q - p * (S + h) - 3, BINS);

    float fa0[HB], fa1[HB + 1], fb0[HB + 2], fb1[HB + 3];
    #pragma unroll
    for (int i = 0; i < HB; ++i) {
        int cc = c0 + i; if (cc >= BINS) cc = BINS - 1;
        fa0[i] = zpg[cc * CST + rA0];
    }
    int idx = ba1;
    #pragma unroll
    for (int i = 0; i < HB + 1; ++i) {
        fa1[i] = zpg[idx * CST + rA1];
        ++idx; if (idx == BINS) idx = 0;
    }
    idx = bb0;
    #pragma unroll
    for (int i = 0; i < HB + 2; ++i) {
        fb0[i] = zpg[idx * CST + rB0];
        ++idx; if (idx == BINS) idx = 0;
    }
    idx = bb1;
    #pragma unroll
    for (int i = 0; i < HB + 3; ++i) {
        fb1[i] = zpg[idx * CST + rB1];
        ++idx; if (idx == BINS) idx = 0;
    }
    __syncthreads();
    #pragma unroll
    for (int i2 = 0; i2 < HB; ++i2) {
        const int c = c0 + i2;
        if (c < BINS) {
            float u0 = fa0[i2] + fa1[i2 + 1];
            float u1 = fa0[i2] + fa1[i2];
            float v0c  = fb0[i2 + 2] + fb1[i2 + 3];
            float v0p  = fb0[i2 + 1] + fb1[i2 + 2];
            float v1p  = fb0[i2 + 1] + fb1[i2 + 1];
            float v1pp = fb0[i2]     + fb1[i2];
            float4 o; o.x = u0 + v0c; o.y = u0 + v0p; o.z = u1 + v1p; o.w = u1 + v1pp;
            *reinterpret_cast<float4*>(&zpg[c * CST + vo]) = o;
        }
    }
    __syncthreads();
}

template<int BINS, int M, int CST, int HSB, int LP>
__device__ __forceinline__
void singleB(float* __restrict__ zpg, int s, int p, int sub)
{
    constexpr int PAIRSB = M / 2;
    const int pr  = sub & (PAIRSB - 1);
    const int chi = sub >> LP;
    const int c0  = chi * HSB;
    const int half = 1 << (s - 1);
    const int qp = pr & (half - 1);
    const int grpbase = (pr >> (s - 1)) << s;
    const int rA = grpbase + qp, rB = rA + half, ro = grpbase + 2 * qp;
    const int shift = (qp + p * half) % BINS;

    float ra[HSB], rb[HSB + 1];
    #pragma unroll
    for (int i = 0; i < HSB; ++i) {
        int cc = c0 + i; if (cc >= BINS) cc = BINS - 1;
        ra[i] = zpg[cc * CST + rA];
    }
    int idx = c0 - shift - 1;
    idx %= BINS; if (idx < 0) idx += BINS;
    #pragma unroll
    for (int i = 0; i < HSB + 1; ++i) {
        rb[i] = zpg[idx * CST + rB];
        ++idx; if (idx == BINS) idx = 0;
    }
    __syncthreads();
    #pragma unroll
    for (int i2 = 0; i2 < HSB; ++i2) {
        const int c = c0 + i2;
        if (c < BINS) {
            float2 o; o.x = ra[i2] + rb[i2 + 1]; o.y = ra[i2] + rb[i2];
            *reinterpret_cast<float2*>(&zpg[c * CST + ro]) = o;
        }
    }
    __syncthreads();
}

template<int BINS, int K, int S0, int CPAD, int OUTOFF>
__device__ __forceinline__
void passB_body(float* __restrict__ zb, float* __restrict__ s_red,
                const unsigned short* __restrict__ scrC, const float2* __restrict__ part,
                float* __restrict__ out, int R, int p_base, int sl)
{
    constexpr int G    = 1 << S0;
    constexpr int M    = 1 << (K - S0);
    constexpr int TS   = K - S0;
    constexpr int P    = 16;
    constexpr int CST  = M + 4;
    constexpr int BCST = BINS * CST;
    constexpr int LQB  = cilog2(M / 4);
    constexpr int CHB  = 32 / (M / 4);
    constexpr int HB   = (BINS + CHB - 1) / CHB;
    constexpr int LPB  = cilog2(M / 2);
    constexpr int CSB  = 32 / (M / 2);
    constexpr int HSB  = (BINS + CSB - 1) / CSB;

    const int t = threadIdx.x;

    if (t < 64) {
        float s = 0.f, s2 = 0.f;
        if (t < 32) { float2 pp = part[sl * STDCH + t]; s = pp.x; s2 = pp.y; }
        #pragma unroll
        for (int off = 16; off > 0; off >>= 1) {
            s  += __shfl_down(s, off, 64);
            s2 += __shfl_down(s2, off, 64);
        }
        if (t == 0) {
            const float n = (float)NLEN;
            s_red[0] = rsqrtf((s2 - s * s / n) / (n - 1.f)) * rsqrtf((float)R);
        }
    }

    {
        constexpr int RUN = P * CPAD / 4;
        constexpr int TOT = M * RUN;
        const unsigned short* base = scrC + (size_t)sl * M * G * CPAD + (size_t)p_base * CPAD;
        for (int i = t; i < TOT; i += 512) {
            const int v = i / RUN, r = i - v * RUN;
            const uint2 d = *reinterpret_cast<const uint2*>(base + (size_t)v * G * CPAD + 4 * r);
            const int e0 = 4 * r;
            const int pl = e0 / CPAD, c = e0 - pl * CPAD;
            float* zp = zb + pl * BCST + v;
            if (c + 0 < BINS) zp[(c + 0) * CST] = __uint_as_float(d.x << 16);
            if (c + 1 < BINS) zp[(c + 1) * CST] = __uint_as_float(d.x & 0xFFFF0000u);
            if (c + 2 < BINS) zp[(c + 2) * CST] = __uint_as_float(d.y << 16);
            if (c + 3 < BINS) zp[(c + 3) * CST] = __uint_as_float(d.y & 0xFFFF0000u);
        }
    }
    __syncthreads();

    const int sub = t & 31, pg = t >> 5;
    const int p = p_base + pg;
    float* zpg = zb + pg * BCST;
    fusedB<BINS, M, CST, HB, LQB>(zpg, 1, p, sub);
    fusedB<BINS, M, CST, HB, LQB>(zpg, 3, p, sub);
    if constexpr (TS == 5) {
        singleB<BINS, M, CST, HSB, LPB>(zpg, 5, p, sub);
    }

    constexpr int ROWS = P * M;
    if (t < ROWS) {
        const int pg2 = t >> TS;
        const int v   = t & (M - 1);
        const float* z = zb + pg2 * BCST;
        float a[BINS];
        #pragma unroll
        for (int c = 0; c < BINS; ++c) a[c] = z[c * CST + v];
        float mx = a[0];
        #pragma unroll
        for (int c = 1; c < BINS; ++c) mx = fmaxf(mx, a[c]);
        constexpr int MIDX = (BINS - 1) / 2;
        #pragma unroll
        for (int i = 0; i <= MIDX; ++i) {
            #pragma unroll
            for (int j = i + 1; j < BINS; ++j) {
                float lo = fminf(a[i], a[j]);
                float hi = fmaxf(a[i], a[j]);
                a[i] = lo; a[j] = hi;
            }
        }
        out[(size_t)sl * OUTROWS + OUTOFF + (size_t)p_base * M + t] = (mx - a[MIDX]) * s_red[0];
    }
}

__global__ __launch_bounds__(512, 6)
void passB_all(const unsigned short* __restrict__ scr, const float2* __restrict__ part,
               float* __restrict__ out)
{
    __shared__ float zb[16 * 13 * 36];   // 29.95 KB (max over configs)
    __shared__ float s_red[1];
    const int b = blockIdx.x;
    if (b < 4096) {
        const int cfg = b >> 10, r = b & 1023, pb = r & 31, sl = r >> 5;
        const int p_base = pb * 16;
        switch (cfg) {
            case 0: passB_body<10, 14, 9, 12, 0>    (zb, s_red, scr + SCROFF[0], part, out, 13107, p_base, sl); break;
            case 1: passB_body<11, 14, 9, 12, 16384>(zb, s_red, scr + SCROFF[1], part, out, 11915, p_base, sl); break;
            case 2: passB_body<12, 14, 9, 12, 32768>(zb, s_red, scr + SCROFF[2], part, out, 10922, p_base, sl); break;
            default: passB_body<13, 14, 9, 16, 49152>(zb, s_red, scr + SCROFF[3], part, out, 10082, p_base, sl); break;
        }
    } else {
        const int b2 = b - 4096;
        const int cfg = b2 >> 9, r = b2 & 511, pb = r & 15, sl = r >> 4;
        const int p_base = pb * 16;
        switch (cfg) {
            case 0: passB_body<16, 12, 8, 16, 65536>(zb, s_red, scr + SCROFF[4], part, out, 4096, p_base, sl); break;
            case 1: passB_body<17, 12, 8, 20, 69632>(zb, s_red, scr + SCROFF[5], part, out, 3855, p_base, sl); break;
            case 2: passB_body<18, 12, 8, 20, 73728>(zb, s_red, scr + SCROFF[6], part, out, 3640, p_base, sl); break;
            default: passB_body<19, 12, 8, 20, 77824>(zb, s_red, scr + SCROFF[7], part, out, 3449, p_base, sl); break;
        }
    }
}

// ---------------- host ----------------
extern "C" void kernel_launch(void* const* d_in, const int* in_sizes, int n_in,
                              void* d_out, int out_size, void* d_ws, size_t ws_size,
                              hipStream_t stream)
{
    (void)in_sizes; (void)n_in; (void)out_size; (void)ws_size;
    const float* x = (const float*)d_in[0];
    float* out  = (float*)d_out;
    float* wsf  = (float*)d_ws;
    float2* part = reinterpret_cast<float2*>(wsf + 64);        // 1024 float2
    unsigned short* scr = reinterpret_cast<unsigned short*>(wsf + 2176);  // 74.5 MB used

    hipLaunchKernelGGL(std_partial, dim3(NSEQ, STDCH), dim3(256), 0, stream, x, part);
    hipLaunchKernelGGL(passA_all, dim3(6144), dim3(512), 0, stream, x, scr);
    hipLaunchKernelGGL(passB_all, dim3(6144), dim3(512), 0, stream, scr, part, out);
}

// Round 8
// 143.828 us; speedup vs baseline: 2.5978x; 1.0887x over previous
//
#include <hip/hip_runtime.h>
#include <cmath>

// FFA regressor for MI355X — 3 dispatches: std_partial, passA_all, passB_all.
// R8: passA runs radix-4 (two stages fused) IN-PLACE using the p=0 form of
// passB's verified fusedB window algebra, plus R5's verified contiguous-float4
// stage-(1,2). All passA row indices go through a bank-swizzle
// swz(r) = r ^ (((r>>4)&7)<<2)  (bijective, quad-contiguous, kills the
// s=3/s=5 quad-row bank conflicts). passB/std unchanged (R5-proven).

constexpr int NSEQ    = 32;
constexpr int NLEN    = 262144;
constexpr int OUTROWS = 81920;
constexpr int STDCH   = 32;

constexpr int cilog2(int v) { int r = 0; while (v > 1) { v >>= 1; ++r; } return r; }

// scratch offsets per config, in bf16 elements (sizes: 32 * 2^K * CPAD)
constexpr size_t SCROFF[8] = {0, 6291456, 12582912, 18874368,
                              27262976, 29360128, 31981568, 34603008};

__device__ __forceinline__ unsigned bf16rne(float f) {
    unsigned u = __float_as_uint(f);
    return (u + 0x7FFFu + ((u >> 16) & 1u)) >> 16;
}
__device__ __forceinline__ unsigned pk2(float lo, float hi) {
    return bf16rne(lo) | (bf16rne(hi) << 16);
}
// bank swizzle for passA rows: bits 2-4 ^= bits 4-6 (upper-triangular -> bijective;
// preserves bits 0-1 so float2/float4 row-quads stay contiguous)
__device__ __forceinline__ int swz(int r) { return r ^ (((r >> 4) & 7) << 2); }

// ---------------- std partials ----------------
__global__ __launch_bounds__(256)
void std_partial(const float* __restrict__ x, float2* __restrict__ part)
{
    const int seq = blockIdx.x, ch = blockIdx.y;
    constexpr int N4 = NLEN / 4 / STDCH;
    const float4* xp = reinterpret_cast<const float4*>(x + (size_t)seq * NLEN) + (size_t)ch * N4;
    float s = 0.f, s2 = 0.f;
    for (int i = threadIdx.x; i < N4; i += 256) {
        float4 v = xp[i];
        s  += (v.x + v.y) + (v.z + v.w);
        s2 += (v.x * v.x + v.y * v.y) + (v.z * v.z + v.w * v.w);
    }
    #pragma unroll
    for (int off = 32; off > 0; off >>= 1) {
        s  += __shfl_down(s, off, 64);
        s2 += __shfl_down(s2, off, 64);
    }
    __shared__ float2 ws[4];
    const int w = threadIdx.x >> 6, l = threadIdx.x & 63;
    if (l == 0) ws[w] = make_float2(s, s2);
    __syncthreads();
    if (threadIdx.x == 0) {
        float a = ws[0].x + ws[1].x + ws[2].x + ws[3].x;
        float b = ws[0].y + ws[1].y + ws[2].y + ws[3].y;
        part[seq * STDCH + ch] = make_float2(a, b);
    }
}

// ---------------- pass A: fused stages (1,2), contiguous float4 reads ----------------
template<int BINS, int G, int HB>
__device__ __forceinline__
void fusedA1ip(float* __restrict__ buf, int Q, int c0)
{
    constexpr int CST = G + 4;
    const int r4 = swz(4 * Q);          // multiple of 4; swz keeps quad contiguous
    float4 ff[HB + 3];
    #pragma unroll
    for (int j = 0; j < HB + 3; ++j) {
        int cc = c0 - 3 + j;
        if (cc < 0) cc += BINS;
        if (cc >= BINS) cc -= BINS;
        ff[j] = *reinterpret_cast<const float4*>(&buf[cc * CST + r4]);
    }
    __syncthreads();
    #pragma unroll
    for (int i = 0; i < HB; ++i) {
        const int c = c0 + i;
        if (c < BINS) {
            float4 f = ff[i + 3], fm1 = ff[i + 2], fm2 = ff[i + 1], fm3 = ff[i];
            float u0 = f.x + f.y;
            float u1 = f.x + fm1.y;
            float4 o;
            o.x = u0 + (f.z + f.w);
            o.y = u0 + (fm1.z + fm1.w);
            o.z = u1 + (fm1.z + fm2.w);
            o.w = u1 + (fm2.z + fm3.w);
            *reinterpret_cast<float4*>(&buf[c * CST + r4]) = o;
        }
    }
    __syncthreads();
}

// ---------------- pass A: fused stages (s, s+1), in-place (fusedB with p=0 + swz) ----------------
template<int BINS, int G, int HB>
__device__ __forceinline__
void fusedAip(float* __restrict__ buf, int s, int Q, int c0)
{
    constexpr int CST = G + 4;
    const int h = 1 << (s - 1), S = 1 << s;
    const int q  = Q & (h - 1);
    const int G2 = (Q >> (s - 1)) << (s + 1);
    const int rA0 = swz(G2 + q),     rA1 = swz(G2 + q + h);
    const int rB0 = swz(G2 + S + q), rB1 = swz(G2 + S + q + h);
    const int vo  = swz(G2 + 4 * q);
    auto mbf = [](int x) { int r = x % BINS; return r < 0 ? r + BINS : r; };
    const int ba1 = mbf(c0 - q - 1);
    const int bb0 = mbf(c0 - 2 * q - 2);
    const int bb1 = mbf(c0 - 3 * q - 3);

    float fa0[HB], fa1[HB + 1], fb0[HB + 2], fb1[HB + 3];
    #pragma unroll
    for (int i = 0; i < HB; ++i) {
        int cc = c0 + i; if (cc >= BINS) cc = BINS - 1;
        fa0[i] = buf[cc * CST + rA0];
    }
    int idx = ba1;
    #pragma unroll
    for (int i = 0; i < HB + 1; ++i) {
        fa1[i] = buf[idx * CST + rA1];
        ++idx; if (idx == BINS) idx = 0;
    }
    idx = bb0;
    #pragma unroll
    for (int i = 0; i < HB + 2; ++i) {
        fb0[i] = buf[idx * CST + rB0];
        ++idx; if (idx == BINS) idx = 0;
    }
    idx = bb1;
    #pragma unroll
    for (int i = 0; i < HB + 3; ++i) {
        fb1[i] = buf[idx * CST + rB1];
        ++idx; if (idx == BINS) idx = 0;
    }
    __syncthreads();
    #pragma unroll
    for (int i = 0; i < HB; ++i) {
        const int c = c0 + i;
        if (c < BINS) {
            float u0 = fa0[i] + fa1[i + 1];
            float u1 = fa0[i] + fa1[i];
            float v0c  = fb0[i + 2] + fb1[i + 3];
            float v0p  = fb0[i + 1] + fb1[i + 2];
            float v1p  = fb0[i + 1] + fb1[i + 1];
            float v1pp = fb0[i]     + fb1[i];
            float4 o; o.x = u0 + v0c; o.y = u0 + v0p; o.z = u1 + v1p; o.w = u1 + v1pp;
            *reinterpret_cast<float4*>(&buf[c * CST + vo]) = o;
        }
    }
    __syncthreads();
}

// ---------------- pass A: single stage 9 (ds2 only), in-place ----------------
template<int BINS, int G, int H1>
__device__ __forceinline__
void stage9IP(float* __restrict__ buf, int pr, int c0)
{
    constexpr int CST = G + 4;
    const int sA = swz(pr);
    const int sB = sA + 256;            // swz(pr+256) == swz(pr)+256 (bit8 doesn't feed swz)
    const int so = swz(2 * pr);         // even; swz(2pr+1) == swz(2pr)+1
    const int shift = pr % BINS;

    float ra[H1], rb[H1 + 1];
    #pragma unroll
    for (int i = 0; i < H1; ++i) {
        int cc = c0 + i; if (cc >= BINS) cc = BINS - 1;
        ra[i] = buf[cc * CST + sA];
    }
    int idx = c0 - shift - 1;
    idx %= BINS; if (idx < 0) idx += BINS;
    #pragma unroll
    for (int i = 0; i < H1 + 1; ++i) {
        rb[i] = buf[idx * CST + sB];
        ++idx; if (idx == BINS) idx = 0;
    }
    __syncthreads();
    #pragma unroll
    for (int i = 0; i < H1; ++i) {
        const int c = c0 + i;
        if (c < BINS) {
            float2 o; o.x = ra[i] + rb[i + 1]; o.y = ra[i] + rb[i];
            *reinterpret_cast<float2*>(&buf[c * CST + so]) = o;
        }
    }
    __syncthreads();
}

// ---------------- pass A body ----------------
template<int DS, int BINS, int K, int S0, int CPAD>
__device__ __forceinline__
void passA_body(float* __restrict__ buf, const float* __restrict__ xs,
                unsigned short* __restrict__ scrC, int R, int blk, int sl)
{
    constexpr int G     = 1 << S0;
    constexpr int M     = 1 << (K - S0);
    constexpr int CST   = G + 4;
    constexpr int QUADS = G / 4;
    constexpr int LQ    = cilog2(QUADS);
    constexpr int CHB   = 512 / QUADS;
    constexpr int HB    = (BINS + CHB - 1) / CHB;
    constexpr int CS1   = 512 / (G / 2);
    constexpr int H1    = (BINS + CS1 - 1) / CS1;
    const int t = threadIdx.x;

    const int fmax = max(0, min(G * BINS, R * BINS - blk * G * BINS));

    // coalesced init: block input is one contiguous x range (exact w=0.5 downsample)
    if constexpr (DS == 2) {
        const float4* src4 = reinterpret_cast<const float4*>(xs + 2 * (size_t)blk * G * BINS);
        constexpr int NF4 = G * BINS / 2;
        for (int i = t; i < NF4; i += 512) {
            const int f0 = 2 * i;
            if (f0 < fmax) {
                float4 v = src4[i];
                int lr = f0 / BINS, c = f0 - lr * BINS;
                buf[c * CST + swz(lr)] = 0.5f * (v.x + v.y);
                if (f0 + 1 < fmax) {
                    int c1 = c + 1, lr1 = lr;
                    if (c1 == BINS) { c1 = 0; ++lr1; }
                    buf[c1 * CST + swz(lr1)] = 0.5f * (v.z + v.w);
                }
            }
        }
    } else {
        const float4* src4 = reinterpret_cast<const float4*>(xs + 4 * (size_t)blk * G * BINS);
        constexpr int NF4 = G * BINS;
        for (int i = t; i < NF4; i += 512) {
            if (i < fmax) {
                float4 v = src4[i];
                int lr = i / BINS, c = i - lr * BINS;
                buf[c * CST + swz(lr)] = 0.5f * (v.y + v.z);
            }
        }
    }
    for (int f = fmax + t; f < G * BINS; f += 512) {
        int lr = f / BINS, c = f - lr * BINS;
        buf[c * CST + swz(lr)] = 0.f;
    }
    __syncthreads();

    // fused radix-4 stages (each contains its own 2 barriers)
    {
        const int Q  = t & (QUADS - 1);
        const int c0 = (t >> LQ) * HB;
        fusedA1ip<BINS, G, HB>(buf, Q, c0);
        fusedAip<BINS, G, HB>(buf, 3, Q, c0);
        fusedAip<BINS, G, HB>(buf, 5, Q, c0);
        fusedAip<BINS, G, HB>(buf, 7, Q, c0);
    }
    if constexpr (S0 == 9) {
        const int pr  = t & (G / 2 - 1);
        const int c01 = (t >> (S0 - 1)) * H1;
        stage9IP<BINS, G, H1>(buf, pr, c01);
    }

    // bf16 writeout: contiguous G*CPAD run per block (reads via swz)
    const float* fin = buf;
    if constexpr (G == 512) {
        const int lr = swz(t);
        unsigned u[CPAD / 2];
        #pragma unroll
        for (int k = 0; k < CPAD / 2; ++k) {
            const int ca = 2 * k, cbn = 2 * k + 1;
            float fa = (ca < BINS)  ? fin[ca * CST + lr]  : 0.f;
            float fb = (cbn < BINS) ? fin[cbn * CST + lr] : 0.f;
            u[k] = pk2(fa, fb);
        }
        unsigned short* dst = scrC + ((size_t)(sl * M + blk) * G + t) * CPAD;
        if constexpr (CPAD == 12) {
            uint2* d2 = reinterpret_cast<uint2*>(dst);
            d2[0] = make_uint2(u[0], u[1]);
            d2[1] = make_uint2(u[2], u[3]);
            d2[2] = make_uint2(u[4], u[5]);
        } else {
            uint4* d4 = reinterpret_cast<uint4*>(dst);
            d4[0] = make_uint4(u[0], u[1], u[2], u[3]);
            d4[1] = make_uint4(u[4], u[5], u[6], u[7]);
        }
    } else {
        const int lrn = t & 255, chh = t >> 8;     // 2 thread-halves per row
        const int lr = swz(lrn);
        constexpr int CH = CPAD / 2;
        unsigned u[CH / 2];
        #pragma unroll
        for (int k = 0; k < CH / 2; ++k) {
            const int ca = chh * CH + 2 * k, cbn = ca + 1;
            float fa = (ca < BINS)  ? fin[ca * CST + lr]  : 0.f;
            float fb = (cbn < BINS) ? fin[cbn * CST + lr] : 0.f;
            u[k] = pk2(fa, fb);
        }
        unsigned short* dst = scrC + ((size_t)(sl * M + blk) * G + lrn) * CPAD + chh * CH;
        if constexpr (CH == 8) {
            *reinterpret_cast<uint4*>(dst) = make_uint4(u[0], u[1], u[2], u[3]);
        } else {
            unsigned* d = reinterpret_cast<unsigned*>(dst);
            #pragma unroll
            for (int k = 0; k < CH / 2; ++k) d[k] = u[k];
        }
    }
}

__global__ __launch_bounds__(512, 6)
void passA_all(const float* __restrict__ x, unsigned short* __restrict__ scr)
{
    __shared__ float buf[13 * 516];   // 26,832 B
    const int b = blockIdx.x;
    if (b < 4096) {
        const int cfg = b >> 10, r = b & 1023, blk = r & 31, sl = r >> 5;
        const float* xs = x + (size_t)sl * NLEN;
        switch (cfg) {
            case 0: passA_body<2, 10, 14, 9, 12>(buf, xs, scr + SCROFF[0], 13107, blk, sl); break;
            case 1: passA_body<2, 11, 14, 9, 12>(buf, xs, scr + SCROFF[1], 11915, blk, sl); break;
            case 2: passA_body<2, 12, 14, 9, 12>(buf, xs, scr + SCROFF[2], 10922, blk, sl); break;
            default: passA_body<2, 13, 14, 9, 16>(buf, xs, scr + SCROFF[3], 10082, blk, sl); break;
        }
    } else {
        const int b2 = b - 4096;
        const int cfg = b2 >> 9, r = b2 & 511, blk = r & 15, sl = r >> 4;
        const float* xs = x + (size_t)sl * NLEN;
        switch (cfg) {
            case 0: passA_body<4, 16, 12, 8, 16>(buf, xs, scr + SCROFF[4], 4096, blk, sl); break;
            case 1: passA_body<4, 17, 12, 8, 20>(buf, xs, scr + SCROFF[5], 3855, blk, sl); break;
            case 2: passA_body<4, 18, 12, 8, 20>(buf, xs, scr + SCROFF[6], 3640, blk, sl); break;
            default: passA_body<4, 19, 12, 8, 20>(buf, xs, scr + SCROFF[7], 3449, blk, sl); break;
        }
    }
}

// ---------------- pass B (unchanged from R5) ----------------
template<int BINS, int M, int CST, int HB, int LQ>
__device__ __forceinline__
void fusedB(float* __restrict__ zpg, int s, int p, int sub)
{
    constexpr int QUADS = M / 4;
    const int Q   = sub & (QUADS - 1);
    const int chi = sub >> LQ;
    const int c0  = chi * HB;
    const int h = 1 << (s - 1), S = 1 << s;
    const int q  = Q & (h - 1);
    const int G2 = (Q >> (s - 1)) << (s + 1);
    const int rA0 = G2 + q, rA1 = rA0 + h, rB0 = G2 + S + q, rB1 = rB0 + h;
    const int vo = G2 + 4 * q;
    auto mbf = [](int x, int B) { int r = x % B; return r < 0 ? r + B : r; };
    const int ba1 = mbf(c0 - q - p * h - 1, BINS);
    const int bb0 = mbf(c0 - 2 * q - p * S - 2, BINS);
    const int bb1 = mbf(c0 - 3 * q - p * (S + h) - 3, BINS);

    float fa0[HB], fa1[HB + 1], fb0[HB + 2], fb1[HB + 3];
    #pragma unroll
    for (int i = 0; i < HB; ++i) {
        int cc = c0 + i; if (cc >= BINS) cc = BINS - 1;
        fa0[i] = zpg[cc * CST + rA0];
    }
    int idx = ba1;
    #pragma unroll
    for (int i = 0; i < HB + 1; ++i) {
        fa1[i] = zpg[idx * CST + rA1];
        ++idx; if (idx == BINS) idx = 0;
    }
    idx = bb0;
    #pragma unroll
    for (int i = 0; i < HB + 2; ++i) {
        fb0[i] = zpg[idx * CST + rB0];
        ++idx; if (idx == BINS) idx = 0;
    }
    idx = bb1;
    #pragma unroll
    for (int i = 0; i < HB + 3; ++i) {
        fb1[i] = zpg[idx * CST + rB1];
        ++idx; if (idx == BINS) idx = 0;
    }
    __syncthreads();
    #pragma unroll
    for (int i2 = 0; i2 < HB; ++i2) {
        const int c = c0 + i2;
        if (c < BINS) {
            float u0 = fa0[i2] + fa1[i2 + 1];
            float u1 = fa0[i2] + fa1[i2];
            float v0c  = fb0[i2 + 2] + fb1[i2 + 3];
            float v0p  = fb0[i2 + 1] + fb1[i2 + 2];
            float v1p  = fb0[i2 + 1] + fb1[i2 + 1];
            float v1pp = fb0[i2]     + fb1[i2];
            float4 o; o.x = u0 + v0c; o.y = u0 + v0p; o.z = u1 + v1p; o.w = u1 + v1pp;
            *reinterpret_cast<float4*>(&zpg[c * CST + vo]) = o;
        }
    }
    __syncthreads();
}

template<int BINS, int M, int CST, int HSB, int LP>
__device__ __forceinline__
void singleB(float* __restrict__ zpg, int s, int p, int sub)
{
    constexpr int PAIRSB = M / 2;
    const int pr  = sub & (PAIRSB - 1);
    const int chi = sub >> LP;
    const int c0  = chi * HSB;
    const int half = 1 << (s - 1);
    const int qp = pr & (half - 1);
    const int grpbase = (pr >> (s - 1)) << s;
    const int rA = grpbase + qp, rB = rA + half, ro = grpbase + 2 * qp;
    const int shift = (qp + p * half) % BINS;

    float ra[HSB], rb[HSB + 1];
    #pragma unroll
    for (int i = 0; i < HSB; ++i) {
        int cc = c0 + i; if (cc >= BINS) cc = BINS - 1;
        ra[i] = zpg[cc * CST + rA];
    }
    int idx = c0 - shift - 1;
    idx %= BINS; if (idx < 0) idx += BINS;
    #pragma unroll
    for (int i = 0; i < HSB + 1; ++i) {
        rb[i] = zpg[idx * CST + rB];
        ++idx; if (idx == BINS) idx = 0;
    }
    __syncthreads();
    #pragma unroll
    for (int i2 = 0; i2 < HSB; ++i2) {
        const int c = c0 + i2;
        if (c < BINS) {
            float2 o; o.x = ra[i2] + rb[i2 + 1]; o.y = ra[i2] + rb[i2];
            *reinterpret_cast<float2*>(&zpg[c * CST + ro]) = o;
        }
    }
    __syncthreads();
}

template<int BINS, int K, int S0, int CPAD, int OUTOFF>
__device__ __forceinline__
void passB_body(float* __restrict__ zb, float* __restrict__ s_red,
                const unsigned short* __restrict__ scrC, const float2* __restrict__ part,
                float* __restrict__ out, int R, int p_base, int sl)
{
    constexpr int G    = 1 << S0;
    constexpr int M    = 1 << (K - S0);
    constexpr int TS   = K - S0;
    constexpr int P    = 16;
    constexpr int CST  = M + 4;
    constexpr int BCST = BINS * CST;
    constexpr int LQB  = cilog2(M / 4);
    constexpr int CHB  = 32 / (M / 4);
    constexpr int HB   = (BINS + CHB - 1) / CHB;
    constexpr int LPB  = cilog2(M / 2);
    constexpr int CSB  = 32 / (M / 2);
    constexpr int HSB  = (BINS + CSB - 1) / CSB;

    const int t = threadIdx.x;

    if (t < 64) {
        float s = 0.f, s2 = 0.f;
        if (t < 32) { float2 pp = part[sl * STDCH + t]; s = pp.x; s2 = pp.y; }
        #pragma unroll
        for (int off = 16; off > 0; off >>= 1) {
            s  += __shfl_down(s, off, 64);
            s2 += __shfl_down(s2, off, 64);
        }
        if (t == 0) {
            const float n = (float)NLEN;
            s_red[0] = rsqrtf((s2 - s * s / n) / (n - 1.f)) * rsqrtf((float)R);
        }
    }

    {
        constexpr int RUN = P * CPAD / 4;
        constexpr int TOT = M * RUN;
        const unsigned short* base = scrC + (size_t)sl * M * G * CPAD + (size_t)p_base * CPAD;
        for (int i = t; i < TOT; i += 512) {
            const int v = i / RUN, r = i - v * RUN;
            const uint2 d = *reinterpret_cast<const uint2*>(base + (size_t)v * G * CPAD + 4 * r);
            const int e0 = 4 * r;
            const int pl = e0 / CPAD, c = e0 - pl * CPAD;
            float* zp = zb + pl * BCST + v;
            if (c + 0 < BINS) zp[(c + 0) * CST] = __uint_as_float(d.x << 16);
            if (c + 1 < BINS) zp[(c + 1) * CST] = __uint_as_float(d.x & 0xFFFF0000u);
            if (c + 2 < BINS) zp[(c + 2) * CST] = __uint_as_float(d.y << 16);
            if (c + 3 < BINS) zp[(c + 3) * CST] = __uint_as_float(d.y & 0xFFFF0000u);
        }
    }
    __syncthreads();

    const int sub = t & 31, pg = t >> 5;
    const int p = p_base + pg;
    float* zpg = zb + pg * BCST;
    fusedB<BINS, M, CST, HB, LQB>(zpg, 1, p, sub);
    fusedB<BINS, M, CST, HB, LQB>(zpg, 3, p, sub);
    if constexpr (TS == 5) {
        singleB<BINS, M, CST, HSB, LPB>(zpg, 5, p, sub);
    }

    constexpr int ROWS = P * M;
    if (t < ROWS) {
        const int pg2 = t >> TS;
        const int v   = t & (M - 1);
        const float* z = zb + pg2 * BCST;
        float a[BINS];
        #pragma unroll
        for (int c = 0; c < BINS; ++c) a[c] = z[c * CST + v];
        float mx = a[0];
        #pragma unroll
        for (int c = 1; c < BINS; ++c) mx = fmaxf(mx, a[c]);
        constexpr int MIDX = (BINS - 1) / 2;
        #pragma unroll
        for (int i = 0; i <= MIDX; ++i) {
            #pragma unroll
            for (int j = i + 1; j < BINS; ++j) {
                float lo = fminf(a[i], a[j]);
                float hi = fmaxf(a[i], a[j]);
                a[i] = lo; a[j] = hi;
            }
        }
        out[(size_t)sl * OUTROWS + OUTOFF + (size_t)p_base * M + t] = (mx - a[MIDX]) * s_red[0];
    }
}

__global__ __launch_bounds__(512, 6)
void passB_all(const unsigned short* __restrict__ scr, const float2* __restrict__ part,
               float* __restrict__ out)
{
    __shared__ float zb[16 * 13 * 36];   // 29.95 KB (max over configs)
    __shared__ float s_red[1];
    const int b = blockIdx.x;
    if (b < 4096) {
        const int cfg = b >> 10, r = b & 1023, pb = r & 31, sl = r >> 5;
        const int p_base = pb * 16;
        switch (cfg) {
            case 0: passB_body<10, 14, 9, 12, 0>    (zb, s_red, scr + SCROFF[0], part, out, 13107, p_base, sl); break;
            case 1: passB_body<11, 14, 9, 12, 16384>(zb, s_red, scr + SCROFF[1], part, out, 11915, p_base, sl); break;
            case 2: passB_body<12, 14, 9, 12, 32768>(zb, s_red, scr + SCROFF[2], part, out, 10922, p_base, sl); break;
            default: passB_body<13, 14, 9, 16, 49152>(zb, s_red, scr + SCROFF[3], part, out, 10082, p_base, sl); break;
        }
    } else {
        const int b2 = b - 4096;
        const int cfg = b2 >> 9, r = b2 & 511, pb = r & 15, sl = r >> 4;
        const int p_base = pb * 16;
        switch (cfg) {
            case 0: passB_body<16, 12, 8, 16, 65536>(zb, s_red, scr + SCROFF[4], part, out, 4096, p_base, sl); break;
            case 1: passB_body<17, 12, 8, 20, 69632>(zb, s_red, scr + SCROFF[5], part, out, 3855, p_base, sl); break;
            case 2: passB_body<18, 12, 8, 20, 73728>(zb, s_red, scr + SCROFF[6], part, out, 3640, p_base, sl); break;
            default: passB_body<19, 12, 8, 20, 77824>(zb, s_red, scr + SCROFF[7], part, out, 3449, p_base, sl); break;
        }
    }
}

// ---------------- host ----------------
extern "C" void kernel_launch(void* const* d_in, const int* in_sizes, int n_in,
                              void* d_out, int out_size, void* d_ws, size_t ws_size,
                              hipStream_t stream)
{
    (void)in_sizes; (void)n_in; (void)out_size; (void)ws_size;
    const float* x = (const float*)d_in[0];
    float* out  = (float*)d_out;
    float* wsf  = (float*)d_ws;
    float2* part = reinterpret_cast<float2*>(wsf + 64);        // 1024 float2
    unsigned short* scr = reinterpret_cast<unsigned short*>(wsf + 2176);  // 74.5 MB used

    hipLaunchKernelGGL(std_partial, dim3(NSEQ, STDCH), dim3(256), 0, stream, x, part);
    hipLaunchKernelGGL(passA_all, dim3(6144), dim3(512), 0, stream, x, scr);
    hipLaunchKernelGGL(passB_all, dim3(6144), dim3(512), 0, stream, scr, part, out);
}